// Round 8
// baseline (301.545 us; speedup 1.0000x reference)
//
#include <hip/hip_runtime.h>
#include <hip/hip_bf16.h>
#include <math.h>

typedef __bf16 bf16x8 __attribute__((ext_vector_type(8)));
typedef __bf16 bf16x4 __attribute__((ext_vector_type(4)));
typedef __bf16 bf16x2 __attribute__((ext_vector_type(2)));
typedef float f32x4 __attribute__((ext_vector_type(4)));

static constexpr int DM = 1024;    // d_model
static constexpr int HD = 64;      // head dim
static constexpr size_t M1 = 1024 * 1024;

// ---------------------------------------------------------------------------
// Fused f32->bf16 convert of all 7 tensors, one launch.
// ---------------------------------------------------------------------------
__global__ void cvt_all(const float* __restrict__ x0, const float* __restrict__ x1,
                        const float* __restrict__ x2, const float* __restrict__ Wq,
                        const float* __restrict__ Wk, const float* __restrict__ Wv,
                        const float* __restrict__ Wo,
                        __bf16* __restrict__ xb0, __bf16* __restrict__ xb1,
                        __bf16* __restrict__ xb2, __bf16* __restrict__ Wqb,
                        __bf16* __restrict__ Wkb, __bf16* __restrict__ Wvb,
                        __bf16* __restrict__ Wob) {
    size_t i = (size_t)(blockIdx.x * blockDim.x + threadIdx.x) * 8;
    const float* in; __bf16* outp; size_t off;
    if      (i < 2 * M1)            { in = x0; outp = xb0; off = i; }
    else if (i < 3 * M1)            { in = x1; outp = xb1; off = i - 2 * M1; }
    else if (i < 3 * M1 + M1 / 2)   { in = x2; outp = xb2; off = i - 3 * M1; }
    else if (i < 6 * M1 + M1 / 2)   { in = Wq; outp = Wqb; off = i - (3 * M1 + M1 / 2); }
    else if (i < 9 * M1 + M1 / 2)   { in = Wk; outp = Wkb; off = i - (6 * M1 + M1 / 2); }
    else if (i < 10 * M1 + M1 / 2)  { in = Wv; outp = Wvb; off = i - (9 * M1 + M1 / 2); }
    else if (i < 11 * M1 + M1 / 2)  { in = Wo; outp = Wob; off = i - (10 * M1 + M1 / 2); }
    else return;
    const float4 a = *reinterpret_cast<const float4*>(in + off);
    const float4 b = *reinterpret_cast<const float4*>(in + off + 4);
    bf16x8 r;
    r[0] = (__bf16)a.x; r[1] = (__bf16)a.y; r[2] = (__bf16)a.z; r[3] = (__bf16)a.w;
    r[4] = (__bf16)b.x; r[5] = (__bf16)b.y; r[6] = (__bf16)b.z; r[7] = (__bf16)b.w;
    *reinterpret_cast<bf16x8*>(outp + off) = r;
}

// ---------------------------------------------------------------------------
// GEMM core: wave computes 64x64 output (4x4 frags of 16x16), BK=32 with
// one-stage-ahead register prefetch. 16 MFMAs per 8-load batch.
// C/D layout: row=(lane>>4)*4+reg, col=lane&15 (m89-verified)
// ---------------------------------------------------------------------------
__device__ __forceinline__ void gemm_core4x4(const __bf16* __restrict__ ap,
                                             const __bf16* __restrict__ wp,
                                             f32x4 (&acc)[4][4]) {
    bf16x8 aC[4], bC[4];
#pragma unroll
    for (int i = 0; i < 4; ++i) {
        aC[i] = *reinterpret_cast<const bf16x8*>(ap + (size_t)i * 16 * DM);
        bC[i] = *reinterpret_cast<const bf16x8*>(wp + (size_t)i * 16 * DM);
    }
    for (int kk = 0; kk < DM - 32; kk += 32) {
        bf16x8 na[4], nb[4];
#pragma unroll
        for (int i = 0; i < 4; ++i) {
            na[i] = *reinterpret_cast<const bf16x8*>(ap + (size_t)i * 16 * DM + kk + 32);
            nb[i] = *reinterpret_cast<const bf16x8*>(wp + (size_t)i * 16 * DM + kk + 32);
        }
#pragma unroll
        for (int mi = 0; mi < 4; ++mi)
#pragma unroll
            for (int ni = 0; ni < 4; ++ni)
                acc[mi][ni] = __builtin_amdgcn_mfma_f32_16x16x32_bf16(aC[mi], bC[ni], acc[mi][ni], 0, 0, 0);
#pragma unroll
        for (int i = 0; i < 4; ++i) { aC[i] = na[i]; bC[i] = nb[i]; }
    }
#pragma unroll
    for (int mi = 0; mi < 4; ++mi)
#pragma unroll
        for (int ni = 0; ni < 4; ++ni)
            acc[mi][ni] = __builtin_amdgcn_mfma_f32_16x16x32_bf16(aC[mi], bC[ni], acc[mi][ni], 0, 0, 0);
}

// ---------------------------------------------------------------------------
// All pre-attention GEMMs in one launch (blockIdx.z = job):
//   z=0,2,4: Q projections (bf16 out, un-roped; rope applied in attention)
//   z=1,3,5: K projections with FUSED RoPE in the epilogue (each wave owns a
//            64-col span = one head; pairs (j, j+32) are frags ni and ni+2,
//            roped on f32 accumulators before the single bf16 rounding)
//   z=6:     V projection -> transposed vt0 [DM][2048] + fused avg-pool
// Block = 128x128 tile (2x2 waves of 64x64).
// ---------------------------------------------------------------------------
__global__ __launch_bounds__(256)
void gemm_pre(const __bf16* __restrict__ xb0, const __bf16* __restrict__ xb1,
              const __bf16* __restrict__ xb2, const __bf16* __restrict__ Wqb,
              const __bf16* __restrict__ Wkb, const __bf16* __restrict__ Wvb,
              const float* __restrict__ bq, const float* __restrict__ bk,
              const float* __restrict__ bv,
              __bf16* __restrict__ qb0, __bf16* __restrict__ kb0,
              __bf16* __restrict__ qb1, __bf16* __restrict__ kb1,
              __bf16* __restrict__ qb2, __bf16* __restrict__ kb2,
              __bf16* __restrict__ vt0, __bf16* __restrict__ vt1,
              __bf16* __restrict__ vt2) {
    const __bf16* A; const __bf16* W; const float* bias; __bf16* out; int M;
    switch (blockIdx.z) {
        case 0:  A = xb0; W = Wqb;          bias = bq;        out = qb0; M = 2048; break;
        case 1:  A = xb0; W = Wkb;          bias = bk;        out = kb0; M = 2048; break;
        case 2:  A = xb1; W = Wqb + M1;     bias = bq + 1024; out = qb1; M = 1024; break;
        case 3:  A = xb1; W = Wkb + M1;     bias = bk + 1024; out = kb1; M = 1024; break;
        case 4:  A = xb2; W = Wqb + 2 * M1; bias = bq + 2048; out = qb2; M = 512;  break;
        case 5:  A = xb2; W = Wkb + 2 * M1; bias = bk + 2048; out = kb2; M = 512;  break;
        default: A = xb0; W = Wvb;          bias = bv;        out = nullptr; M = 2048; break;
    }
    if ((int)blockIdx.y * 128 >= M) return;
    const int lane = threadIdx.x & 63;
    const int w = threadIdx.x >> 6;
    const int g = lane >> 4, t = lane & 15;
    const int rb = blockIdx.y * 128 + (w >> 1) * 64;
    const int cb = blockIdx.x * 128 + (w & 1) * 64;   // multiple of 64 -> one head
    f32x4 acc[4][4] = {};
    gemm_core4x4(A + (size_t)(rb + t) * DM + g * 8, W + (size_t)(cb + t) * DM + g * 8, acc);

    if (blockIdx.z == 6) {
        // V projection epilogue: transposed store + fused avg-pool
#pragma unroll
        for (int ni = 0; ni < 4; ++ni) {
            const int col = cb + ni * 16 + t;          // d dim
            const float bb = bias[col];
#pragma unroll
            for (int mi = 0; mi < 4; ++mi) {
                const int row0 = rb + mi * 16 + g * 4; // n dim, divisible by 4
                const f32x4 a = acc[mi][ni];
                bf16x4 pk;
#pragma unroll
                for (int r = 0; r < 4; ++r) pk[r] = (__bf16)(a[r] + bb);
                *reinterpret_cast<bf16x4*>(vt0 + (size_t)col * 2048 + row0) = pk;
                bf16x2 p2;
                p2[0] = (__bf16)(0.5f * (a[0] + a[1]) + bb);
                p2[1] = (__bf16)(0.5f * (a[2] + a[3]) + bb);
                *reinterpret_cast<bf16x2*>(vt1 + (size_t)col * 1024 + row0 / 2) = p2;
                vt2[(size_t)col * 512 + row0 / 4] =
                    (__bf16)(0.25f * (a[0] + a[1] + a[2] + a[3]) + bb);
            }
        }
    } else if (blockIdx.z & 1) {
        // K projection epilogue with fused RoPE
        const float ps = (float)(1 << (blockIdx.z >> 1));   // 1,2,4
#pragma unroll
        for (int ni = 0; ni < 2; ++ni) {
            const int j = ni * 16 + t;                      // [0,32) within head
            const float invf = __expf(-(float)j * 0.28782313662425576f);
            const float b1 = bias[cb + j];
            const float b2 = bias[cb + j + 32];
#pragma unroll
            for (int mi = 0; mi < 4; ++mi) {
#pragma unroll
                for (int r = 0; r < 4; ++r) {
                    const int row = rb + mi * 16 + g * 4 + r;
                    float c, s;
                    __sincosf((float)row * ps * invf, &s, &c);
                    const float x1 = acc[mi][ni][r] + b1;
                    const float x2 = acc[mi][ni + 2][r] + b2;
                    out[(size_t)row * DM + cb + j]      = (__bf16)(x1 * c - x2 * s);
                    out[(size_t)row * DM + cb + j + 32] = (__bf16)(x1 * s + x2 * c);
                }
            }
        }
    } else {
        // Q projection epilogue (plain)
#pragma unroll
        for (int ni = 0; ni < 4; ++ni) {
            const int col = cb + ni * 16 + t;
            const float bb = bias[col];
#pragma unroll
            for (int mi = 0; mi < 4; ++mi) {
                const int row0 = rb + mi * 16 + g * 4;
#pragma unroll
                for (int r = 0; r < 4; ++r)
                    out[(size_t)(row0 + r) * DM + col] = (__bf16)(acc[mi][ni][r] + bb);
            }
        }
    }
}

// ---------------------------------------------------------------------------
// MFMA flash attention v4: split-K + head->XCD affinity swizzle.
// 1-D grid of 3584 blocks. bid -> xcd = bid&7, job = xcd*448 + bid>>3;
// job -> (head = job/224, scale+qtile from job%224). Each XCD owns 2 heads
// (all scales): per-XCD K/V working set ~1.75 MB << 4 MB L2 -> L2-resident.
// Block = (16-row q-tile, head); 4 waves split key tiles round-robin; NO-MAX
// softmax (scores bounded) -> partials combine additively through LDS.
// ---------------------------------------------------------------------------
__global__ __launch_bounds__(256)
void attn_all(const __bf16* __restrict__ qb0, const __bf16* __restrict__ kb0,
              const __bf16* __restrict__ vt0, __bf16* __restrict__ ctx0,
              const __bf16* __restrict__ qb1, const __bf16* __restrict__ kb1,
              const __bf16* __restrict__ vt1, __bf16* __restrict__ ctx1,
              const __bf16* __restrict__ qb2, const __bf16* __restrict__ kb2,
              const __bf16* __restrict__ vt2, __bf16* __restrict__ ctx2) {
    __shared__ __align__(16) float lds[4 * 1344];   // 21 KB
    const int bid = blockIdx.x;
    const int job = (bid & 7) * 448 + (bid >> 3);
    const int h = job / 224;
    int rem = job % 224;
    const __bf16 *qb, *kb, *vt; __bf16* ctx; int N, nq; float posScale;
    if (rem < 128) {
        qb = qb0; kb = kb0; vt = vt0; ctx = ctx0; N = 2048; posScale = 1.f; nq = 128;
    } else if (rem < 192) {
        rem -= 128;
        qb = qb1; kb = kb1; vt = vt1; ctx = ctx1; N = 1024; posScale = 2.f; nq = 64;
    } else {
        rem -= 192;
        qb = qb2; kb = kb2; vt = vt2; ctx = ctx2; N = 512;  posScale = 4.f; nq = 32;
    }
    const int qt = (rem & 1) ? (nq - 1 - (rem >> 1)) : (rem >> 1);  // heavy/light pair
    const int lane = threadIdx.x & 63;
    const int w = threadIdx.x >> 6;
    const int q0 = qt * 16;
    const int g = lane >> 4;
    const int t = lane & 15;

    // Q load + rope + 1/8 scale
    const __bf16* qp = qb + (size_t)(q0 + t) * DM + h * HD + g * 8;
    const bf16x8 xq0 = *reinterpret_cast<const bf16x8*>(qp);
    const bf16x8 xq1 = *reinterpret_cast<const bf16x8*>(qp + 32);
    bf16x8 aq0, aq1;
    const float pn = (float)(q0 + t) * posScale;
#pragma unroll
    for (int i = 0; i < 8; ++i) {
        const int j = g * 8 + i;
        const float invf = __expf(-(float)j * 0.28782313662425576f);
        float c, sn;
        __sincosf(pn * invf, &sn, &c);
        const float x1 = (float)xq0[i], x2 = (float)xq1[i];
        aq0[i] = (__bf16)((x1 * c - x2 * sn) * 0.125f);
        aq1[i] = (__bf16)((x1 * sn + x2 * c) * 0.125f);
    }

    f32x4 o0 = {0,0,0,0}, o1 = {0,0,0,0}, o2 = {0,0,0,0}, o3 = {0,0,0,0};
    float lsum[4] = {0.f, 0.f, 0.f, 0.f};
    float* pl = lds + w * 1344;

    const __bf16* kbase = kb + h * HD + g * 8;
    const __bf16* vbase = vt + ((size_t)h * HD + t) * N + g * 8;
    const int ktiles = (q0 + 47) >> 5;

    bf16x8 k0a = *reinterpret_cast<const bf16x8*>(kbase + (size_t)(w * 32 + t) * DM);
    bf16x8 k0b = *reinterpret_cast<const bf16x8*>(kbase + (size_t)(w * 32 + t) * DM + 32);
    bf16x8 k1a = *reinterpret_cast<const bf16x8*>(kbase + (size_t)(w * 32 + 16 + t) * DM);
    bf16x8 k1b = *reinterpret_cast<const bf16x8*>(kbase + (size_t)(w * 32 + 16 + t) * DM + 32);

    for (int kt = w; kt < ktiles; kt += 4) {
        const int j0 = kt * 32;
        const int jn = (kt + 4 < ktiles) ? j0 + 128 : j0;
        const bf16x8 nk0a = *reinterpret_cast<const bf16x8*>(kbase + (size_t)(jn + t) * DM);
        const bf16x8 nk0b = *reinterpret_cast<const bf16x8*>(kbase + (size_t)(jn + t) * DM + 32);
        const bf16x8 nk1a = *reinterpret_cast<const bf16x8*>(kbase + (size_t)(jn + 16 + t) * DM);
        const bf16x8 nk1b = *reinterpret_cast<const bf16x8*>(kbase + (size_t)(jn + 16 + t) * DM + 32);
        const __bf16* vp = vbase + j0;
        const bf16x8 va = *reinterpret_cast<const bf16x8*>(vp);
        const bf16x8 vb = *reinterpret_cast<const bf16x8*>(vp + (size_t)16 * N);
        const bf16x8 vc = *reinterpret_cast<const bf16x8*>(vp + (size_t)32 * N);
        const bf16x8 vd = *reinterpret_cast<const bf16x8*>(vp + (size_t)48 * N);

        f32x4 s0 = {0,0,0,0}, s1 = {0,0,0,0};
        s0 = __builtin_amdgcn_mfma_f32_16x16x32_bf16(aq0, k0a, s0, 0,0,0);
        s0 = __builtin_amdgcn_mfma_f32_16x16x32_bf16(aq1, k0b, s0, 0,0,0);
        s1 = __builtin_amdgcn_mfma_f32_16x16x32_bf16(aq0, k1a, s1, 0,0,0);
        s1 = __builtin_amdgcn_mfma_f32_16x16x32_bf16(aq1, k1b, s1, 0,0,0);

#pragma unroll
        for (int r = 0; r < 4; ++r) {
            const int qg = q0 + g * 4 + r;
            s0[r] = (j0 + t      <= qg) ? __expf(s0[r]) : 0.f;
            s1[r] = (j0 + 16 + t <= qg) ? __expf(s1[r]) : 0.f;
            lsum[r] += s0[r] + s1[r];
            pl[(g * 4 + r) * 36 + t]      = s0[r];
            pl[(g * 4 + r) * 36 + 16 + t] = s1[r];
        }
        const float* rp = pl + t * 36 + g * 8;
        const float4 pa_ = *reinterpret_cast<const float4*>(rp);
        const float4 pb_ = *reinterpret_cast<const float4*>(rp + 4);
        bf16x8 pa;
        pa[0] = (__bf16)pa_.x; pa[1] = (__bf16)pa_.y; pa[2] = (__bf16)pa_.z; pa[3] = (__bf16)pa_.w;
        pa[4] = (__bf16)pb_.x; pa[5] = (__bf16)pb_.y; pa[6] = (__bf16)pb_.z; pa[7] = (__bf16)pb_.w;

        o0 = __builtin_amdgcn_mfma_f32_16x16x32_bf16(pa, va, o0, 0,0,0);
        o1 = __builtin_amdgcn_mfma_f32_16x16x32_bf16(pa, vb, o1, 0,0,0);
        o2 = __builtin_amdgcn_mfma_f32_16x16x32_bf16(pa, vc, o2, 0,0,0);
        o3 = __builtin_amdgcn_mfma_f32_16x16x32_bf16(pa, vd, o3, 0,0,0);

        k0a = nk0a; k0b = nk0b; k1a = nk1a; k1b = nk1b;
    }

    float* my = lds + w * 1344 + lane * 21;
#pragma unroll
    for (int r = 0; r < 4; ++r) {
        my[r]      = o0[r];
        my[4 + r]  = o1[r];
        my[8 + r]  = o2[r];
        my[12 + r] = o3[r];
        my[16 + r] = lsum[r];
    }
    __syncthreads();
    f32x4 ow = {0,0,0,0};
    float lp[4] = {0,0,0,0};
#pragma unroll
    for (int w2 = 0; w2 < 4; ++w2) {
        const float* src = lds + w2 * 1344 + lane * 21;
#pragma unroll
        for (int r = 0; r < 4; ++r) {
            ow[r] += src[w * 4 + r];
            lp[r] += src[16 + r];
        }
    }
#pragma unroll
    for (int off = 1; off < 16; off <<= 1)
#pragma unroll
        for (int r = 0; r < 4; ++r) lp[r] += __shfl_xor(lp[r], off);
#pragma unroll
    for (int r = 0; r < 4; ++r)
        ctx[(size_t)(q0 + g * 4 + r) * DM + h * HD + w * 16 + t] =
            (__bf16)(ow[r] / lp[r]);
}

// ---------------------------------------------------------------------------
// All 3 output projections in one launch (blockIdx.z = scale). f32 out.
// Block = 128x128 tile (2x2 waves of 64x64).
// ---------------------------------------------------------------------------
__global__ __launch_bounds__(256)
void gemm_out_all(const __bf16* __restrict__ c0, const __bf16* __restrict__ c1,
                  const __bf16* __restrict__ c2, const __bf16* __restrict__ Wob,
                  const float* __restrict__ bo, float* __restrict__ out) {
    const __bf16* A; float* o; int M;
    switch (blockIdx.z) {
        case 0:  A = c0; o = out;             M = 2048; break;
        case 1:  A = c1; o = out + 2048 * DM; M = 1024; break;
        default: A = c2; o = out + 3072 * DM; M = 512;  break;
    }
    if ((int)blockIdx.y * 128 >= M) return;
    const int lane = threadIdx.x & 63;
    const int w = threadIdx.x >> 6;
    const int g = lane >> 4, t = lane & 15;
    const int rb = blockIdx.y * 128 + (w >> 1) * 64;
    const int cb = blockIdx.x * 128 + (w & 1) * 64;
    f32x4 acc[4][4] = {};
    gemm_core4x4(A + (size_t)(rb + t) * DM + g * 8, Wob + (size_t)(cb + t) * DM + g * 8, acc);
#pragma unroll
    for (int ni = 0; ni < 4; ++ni) {
        const int col = cb + ni * 16 + t;
        const float bb = bo[col];
#pragma unroll
        for (int mi = 0; mi < 4; ++mi) {
            const int row0 = rb + mi * 16 + g * 4;
#pragma unroll
            for (int r = 0; r < 4; ++r)
                o[(size_t)(row0 + r) * DM + col] = acc[mi][ni][r] + bb;
        }
    }
}

// ---------------------------------------------------------------------------
extern "C" void kernel_launch(void* const* d_in, const int* in_sizes, int n_in,
                              void* d_out, int out_size, void* d_ws, size_t ws_size,
                              hipStream_t stream) {
    const float* x0 = (const float*)d_in[0];
    const float* x1 = (const float*)d_in[1];
    const float* x2 = (const float*)d_in[2];
    const float* Wq = (const float*)d_in[3];
    const float* bq = (const float*)d_in[4];
    const float* Wk = (const float*)d_in[5];
    const float* bk = (const float*)d_in[6];
    const float* Wv = (const float*)d_in[7];
    const float* bv = (const float*)d_in[8];
    const float* Wo = (const float*)d_in[9];
    const float* bo = (const float*)d_in[10];
    float* out = (float*)d_out;

    // bf16 workspace, ~39 MB
    __bf16* xb0 = (__bf16*)d_ws;        // 2M
    __bf16* xb1 = xb0 + 2 * M1;         // 1M
    __bf16* xb2 = xb1 + M1;             // 0.5M
    __bf16* Wqb = xb2 + M1 / 2;         // 3M
    __bf16* Wkb = Wqb + 3 * M1;         // 3M
    __bf16* Wvb = Wkb + 3 * M1;         // 1M
    __bf16* Wob = Wvb + M1;             // 1M
    __bf16* vt0 = Wob + M1;             // 2M
    __bf16* vt1 = vt0 + 2 * M1;         // 1M
    __bf16* vt2 = vt1 + M1;             // 0.5M
    __bf16* qb0 = vt2 + M1 / 2;         // 2M
    __bf16* kb0 = qb0 + 2 * M1;         // 2M
    __bf16* qb1 = kb0 + 2 * M1;         // 1M
    __bf16* kb1 = qb1 + M1;             // 1M
    __bf16* qb2 = kb1 + M1;             // 0.5M
    __bf16* kb2 = qb2 + M1 / 2;         // 0.5M

    // 1. convert everything to bf16
    cvt_all<<<5888, 256, 0, stream>>>(x0, x1, x2, Wq, Wk, Wv, Wo,
                                      xb0, xb1, xb2, Wqb, Wkb, Wvb, Wob);
    // 2. all pre-attention GEMMs (Q | K-with-rope | V-with-pool), one launch
    gemm_pre<<<dim3(8, 16, 7), 256, 0, stream>>>(xb0, xb1, xb2, Wqb, Wkb, Wvb,
                                                 bq, bk, bv,
                                                 qb0, kb0, qb1, kb1, qb2, kb2,
                                                 vt0, vt1, vt2);
    // 3. attention, all scales, head->XCD affinity swizzle (1-D grid)
    attn_all<<<3584, 256, 0, stream>>>(qb0, kb0, vt0, qb0,
                                       qb1, kb1, vt1, qb1,
                                       qb2, kb2, vt2, qb2);
    // 4. output projections (one launch, 3 jobs), f32 into d_out
    gemm_out_all<<<dim3(8, 16, 3), 256, 0, stream>>>(qb0, qb1, qb2, Wob, bo, out);
}

// Round 10
// 244.259 us; speedup vs baseline: 1.2345x; 1.2345x over previous
//
#include <hip/hip_runtime.h>
#include <hip/hip_bf16.h>
#include <math.h>

typedef __bf16 bf16x8 __attribute__((ext_vector_type(8)));
typedef __bf16 bf16x4 __attribute__((ext_vector_type(4)));
typedef __bf16 bf16x2 __attribute__((ext_vector_type(2)));
typedef float f32x4 __attribute__((ext_vector_type(4)));
typedef float f32x16 __attribute__((ext_vector_type(16)));

static constexpr int DM = 1024;    // d_model
static constexpr int HD = 64;      // head dim
static constexpr size_t M1 = 1024 * 1024;

// pack two f32 -> u32 of two bf16 (compiler emits v_cvt_pk_bf16_f32)
__device__ __forceinline__ unsigned pk2(float a, float b) {
    union { __bf16 h[2]; unsigned u; } t;
    t.h[0] = (__bf16)a; t.h[1] = (__bf16)b;
    return t.u;
}

// ---------------------------------------------------------------------------
// Fused f32->bf16 convert of all 7 tensors, one launch.
// ---------------------------------------------------------------------------
__global__ void cvt_all(const float* __restrict__ x0, const float* __restrict__ x1,
                        const float* __restrict__ x2, const float* __restrict__ Wq,
                        const float* __restrict__ Wk, const float* __restrict__ Wv,
                        const float* __restrict__ Wo,
                        __bf16* __restrict__ xb0, __bf16* __restrict__ xb1,
                        __bf16* __restrict__ xb2, __bf16* __restrict__ Wqb,
                        __bf16* __restrict__ Wkb, __bf16* __restrict__ Wvb,
                        __bf16* __restrict__ Wob) {
    size_t i = (size_t)(blockIdx.x * blockDim.x + threadIdx.x) * 8;
    const float* in; __bf16* outp; size_t off;
    if      (i < 2 * M1)            { in = x0; outp = xb0; off = i; }
    else if (i < 3 * M1)            { in = x1; outp = xb1; off = i - 2 * M1; }
    else if (i < 3 * M1 + M1 / 2)   { in = x2; outp = xb2; off = i - 3 * M1; }
    else if (i < 6 * M1 + M1 / 2)   { in = Wq; outp = Wqb; off = i - (3 * M1 + M1 / 2); }
    else if (i < 9 * M1 + M1 / 2)   { in = Wk; outp = Wkb; off = i - (6 * M1 + M1 / 2); }
    else if (i < 10 * M1 + M1 / 2)  { in = Wv; outp = Wvb; off = i - (9 * M1 + M1 / 2); }
    else if (i < 11 * M1 + M1 / 2)  { in = Wo; outp = Wob; off = i - (10 * M1 + M1 / 2); }
    else return;
    const float4 a = *reinterpret_cast<const float4*>(in + off);
    const float4 b = *reinterpret_cast<const float4*>(in + off + 4);
    bf16x8 r;
    r[0] = (__bf16)a.x; r[1] = (__bf16)a.y; r[2] = (__bf16)a.z; r[3] = (__bf16)a.w;
    r[4] = (__bf16)b.x; r[5] = (__bf16)b.y; r[6] = (__bf16)b.z; r[7] = (__bf16)b.w;
    *reinterpret_cast<bf16x8*>(outp + off) = r;
}

// ---------------------------------------------------------------------------
// GEMM core: wave computes 64x64 output (4x4 frags), BK=32 register prefetch.
// C/D layout: row=(lane>>4)*4+reg, col=lane&15 (m89-verified)
// ---------------------------------------------------------------------------
__device__ __forceinline__ void gemm_core4x4(const __bf16* __restrict__ ap,
                                             const __bf16* __restrict__ wp,
                                             f32x4 (&acc)[4][4]) {
    bf16x8 aC[4], bC[4];
#pragma unroll
    for (int i = 0; i < 4; ++i) {
        aC[i] = *reinterpret_cast<const bf16x8*>(ap + (size_t)i * 16 * DM);
        bC[i] = *reinterpret_cast<const bf16x8*>(wp + (size_t)i * 16 * DM);
    }
    for (int kk = 0; kk < DM - 32; kk += 32) {
        bf16x8 na[4], nb[4];
#pragma unroll
        for (int i = 0; i < 4; ++i) {
            na[i] = *reinterpret_cast<const bf16x8*>(ap + (size_t)i * 16 * DM + kk + 32);
            nb[i] = *reinterpret_cast<const bf16x8*>(wp + (size_t)i * 16 * DM + kk + 32);
        }
#pragma unroll
        for (int mi = 0; mi < 4; ++mi)
#pragma unroll
            for (int ni = 0; ni < 4; ++ni)
                acc[mi][ni] = __builtin_amdgcn_mfma_f32_16x16x32_bf16(aC[mi], bC[ni], acc[mi][ni], 0, 0, 0);
#pragma unroll
        for (int i = 0; i < 4; ++i) { aC[i] = na[i]; bC[i] = nb[i]; }
    }
#pragma unroll
    for (int mi = 0; mi < 4; ++mi)
#pragma unroll
        for (int ni = 0; ni < 4; ++ni)
            acc[mi][ni] = __builtin_amdgcn_mfma_f32_16x16x32_bf16(aC[mi], bC[ni], acc[mi][ni], 0, 0, 0);
}

// ---------------------------------------------------------------------------
// All pre-attention GEMMs (blockIdx.z = job):
//   z=0,2,4: Q projections with FUSED RoPE + 1/8 scale (scales 0,1,2)
//   z=1,3,5: K projections with FUSED RoPE
//   z=6:     V projection -> transposed vt0 + fused avg-pool into vt1, vt2
// Block = 128x128 tile (2x2 waves of 64x64); each wave's 64-col span = 1 head.
// ---------------------------------------------------------------------------
__global__ __launch_bounds__(256)
void gemm_pre(const __bf16* __restrict__ xb0, const __bf16* __restrict__ xb1,
              const __bf16* __restrict__ xb2, const __bf16* __restrict__ Wqb,
              const __bf16* __restrict__ Wkb, const __bf16* __restrict__ Wvb,
              const float* __restrict__ bq, const float* __restrict__ bk,
              const float* __restrict__ bv,
              __bf16* __restrict__ qb0, __bf16* __restrict__ kb0,
              __bf16* __restrict__ qb1, __bf16* __restrict__ kb1,
              __bf16* __restrict__ qb2, __bf16* __restrict__ kb2,
              __bf16* __restrict__ vt0, __bf16* __restrict__ vt1,
              __bf16* __restrict__ vt2) {
    const __bf16* A; const __bf16* W; const float* bias; __bf16* out; int M;
    switch (blockIdx.z) {
        case 0:  A = xb0; W = Wqb;          bias = bq;        out = qb0; M = 2048; break;
        case 1:  A = xb0; W = Wkb;          bias = bk;        out = kb0; M = 2048; break;
        case 2:  A = xb1; W = Wqb + M1;     bias = bq + 1024; out = qb1; M = 1024; break;
        case 3:  A = xb1; W = Wkb + M1;     bias = bk + 1024; out = kb1; M = 1024; break;
        case 4:  A = xb2; W = Wqb + 2 * M1; bias = bq + 2048; out = qb2; M = 512;  break;
        case 5:  A = xb2; W = Wkb + 2 * M1; bias = bk + 2048; out = kb2; M = 512;  break;
        default: A = xb0; W = Wvb;          bias = bv;        out = nullptr; M = 2048; break;
    }
    if ((int)blockIdx.y * 128 >= M) return;
    const int lane = threadIdx.x & 63;
    const int w = threadIdx.x >> 6;
    const int g = lane >> 4, t = lane & 15;
    const int rb = blockIdx.y * 128 + (w >> 1) * 64;
    const int cb = blockIdx.x * 128 + (w & 1) * 64;   // head-aligned span
    f32x4 acc[4][4] = {};
    gemm_core4x4(A + (size_t)(rb + t) * DM + g * 8, W + (size_t)(cb + t) * DM + g * 8, acc);

    if (blockIdx.z == 6) {
        // V projection epilogue: transposed store + fused avg-pool
#pragma unroll
        for (int ni = 0; ni < 4; ++ni) {
            const int col = cb + ni * 16 + t;          // d dim
            const float bb = bias[col];
#pragma unroll
            for (int mi = 0; mi < 4; ++mi) {
                const int row0 = rb + mi * 16 + g * 4; // n dim
                const f32x4 a = acc[mi][ni];
                bf16x4 pk;
#pragma unroll
                for (int r = 0; r < 4; ++r) pk[r] = (__bf16)(a[r] + bb);
                *reinterpret_cast<bf16x4*>(vt0 + (size_t)col * 2048 + row0) = pk;
                bf16x2 p2;
                p2[0] = (__bf16)(0.5f * (a[0] + a[1]) + bb);
                p2[1] = (__bf16)(0.5f * (a[2] + a[3]) + bb);
                *reinterpret_cast<bf16x2*>(vt1 + (size_t)col * 1024 + row0 / 2) = p2;
                vt2[(size_t)col * 512 + row0 / 4] =
                    (__bf16)(0.25f * (a[0] + a[1] + a[2] + a[3]) + bb);
            }
        }
    } else {
        // Q/K epilogue with fused RoPE; Q additionally scaled by 1/8
        const float qmul = (blockIdx.z & 1) ? 1.0f : 0.125f;
        const float ps = (float)(1 << (blockIdx.z >> 1));   // 1,2,4
#pragma unroll
        for (int ni = 0; ni < 2; ++ni) {
            const int j = ni * 16 + t;                      // [0,32) within head
            const float invf = __expf(-(float)j * 0.28782313662425576f);
            const float b1 = bias[cb + j];
            const float b2 = bias[cb + j + 32];
#pragma unroll
            for (int mi = 0; mi < 4; ++mi) {
#pragma unroll
                for (int r = 0; r < 4; ++r) {
                    const int row = rb + mi * 16 + g * 4 + r;
                    float c, s;
                    __sincosf((float)row * ps * invf, &s, &c);
                    const float x1 = acc[mi][ni][r] + b1;
                    const float x2 = acc[mi][ni + 2][r] + b2;
                    out[(size_t)row * DM + cb + j]      = (__bf16)((x1 * c - x2 * s) * qmul);
                    out[(size_t)row * DM + cb + j + 32] = (__bf16)((x1 * s + x2 * c) * qmul);
                }
            }
        }
    }
}

// ---------------------------------------------------------------------------
// MFMA flash attention v6: 32-row waves, swapped-operand QK^T, lane-local
// softmax, per-wave LDS P-bounce (layout-proof PV).
// Block = (32-row qtile, head); 4 waves split key tiles round-robin (split-K;
// NO-MAX softmax -> partials add).
// QK^T: p = mfma32(K, Q): lane l holds scores for q-row q0+(l&31), keys
//   j0 + (r&3)+8*(r>>2)+4*(l>>5) (m74/m101 C/D layout, HW-verified).
// P path: pack bf16 pairs, write to per-wave LDS tile [32 q][36 bf16] at the
//   key positions (C/D addresses), read back contiguous-8 per lane — the SAME
//   load convention as the V frags, so any HW k-permutation of the MFMA
//   operand wiring cancels (dot-product invariance). No barrier needed:
//   within-wave LDS write->read is ordered by lgkmcnt.
// PV: O^T[d][q] accumulated as mfma32(V^T-frag, P-frag, o).
// Final 4-wave split-K combine through a separate LDS region.
// XCD affinity: 1792 blocks = 8 x 224; job=(bid&7)*224+(bid>>3); 2 heads/XCD.
// ---------------------------------------------------------------------------
__global__ __launch_bounds__(256)
void attn_all(const __bf16* __restrict__ qb0, const __bf16* __restrict__ kb0,
              const __bf16* __restrict__ vt0, __bf16* __restrict__ ctx0,
              const __bf16* __restrict__ qb1, const __bf16* __restrict__ kb1,
              const __bf16* __restrict__ vt1, __bf16* __restrict__ ctx1,
              const __bf16* __restrict__ qb2, const __bf16* __restrict__ kb2,
              const __bf16* __restrict__ vt2, __bf16* __restrict__ ctx2) {
    __shared__ __align__(16) unsigned pb[4 * 32 * 18];  // P bounce: 9 KB (per-wave private)
    __shared__ __align__(16) float cmb[4 * 64 * 33];    // split-K combine: 33 KB
    const int bid = blockIdx.x;
    const int job = (bid & 7) * 224 + (bid >> 3);
    const int h = job / 112;
    int rem = job % 112;
    const __bf16 *qb, *kb, *vt; __bf16* ctx; int N, nq;
    if (rem < 64)      { qb = qb0; kb = kb0; vt = vt0; ctx = ctx0; N = 2048; nq = 64; }
    else if (rem < 96) { rem -= 64; qb = qb1; kb = kb1; vt = vt1; ctx = ctx1; N = 1024; nq = 32; }
    else               { rem -= 96; qb = qb2; kb = kb2; vt = vt2; ctx = ctx2; N = 512;  nq = 16; }
    const int qt = (rem & 1) ? (nq - 1 - (rem >> 1)) : (rem >> 1);  // heavy/light pair
    const int lane = threadIdx.x & 63;
    const int w = threadIdx.x >> 6;
    const int q0 = qt * 32;
    const int lq = lane & 31;      // q-row index (C/D col)
    const int hi = lane >> 5;      // half-wave

    // Q B-frags, 4 d-chunks: lane holds Q[q0+lq][h*64 + dc*16 + hi*8 + 0..7]
    const __bf16* qp = qb + (size_t)(q0 + lq) * DM + h * HD + hi * 8;
    bf16x8 qf[4];
#pragma unroll
    for (int dc = 0; dc < 4; ++dc)
        qf[dc] = *reinterpret_cast<const bf16x8*>(qp + dc * 16);

    f32x16 o0 = {}, o1 = {};
    float lsum = 0.f;

    const __bf16* kbase = kb + h * HD + hi * 8;
    const __bf16* vr0 = vt + ((size_t)(h * HD + lq)) * N + hi * 8;       // d 0..31
    const __bf16* vr1 = vt + ((size_t)(h * HD + 32 + lq)) * N + hi * 8;  // d 32..63
    const int ktiles = qt + 1;   // covers keys 0 .. q0+31

    unsigned* pw = pb + (w * 32 + lq) * 18;             // this lane's P row
    const __bf16* prb = (const __bf16*)pw;              // same row, bf16 view

    // preload K tile kt=w (keys < 128 <= N, always in-bounds)
    bf16x8 kf[4];
    {
        const __bf16* kp = kbase + (size_t)(w * 32 + lq) * DM;
#pragma unroll
        for (int dc = 0; dc < 4; ++dc)
            kf[dc] = *reinterpret_cast<const bf16x8*>(kp + dc * 16);
    }

    for (int kt = w; kt < ktiles; kt += 4) {
        const int j0 = kt * 32;
        const int jn = (kt + 4 < ktiles) ? j0 + 128 : j0;   // clamped prefetch
        bf16x8 nk[4];
        {
            const __bf16* kp = kbase + (size_t)(jn + lq) * DM;
#pragma unroll
            for (int dc = 0; dc < 4; ++dc)
                nk[dc] = *reinterpret_cast<const bf16x8*>(kp + dc * 16);
        }
        // V^T A-frags (contiguous-8 per lane along keys)
        const bf16x8 v00 = *reinterpret_cast<const bf16x8*>(vr0 + j0);
        const bf16x8 v01 = *reinterpret_cast<const bf16x8*>(vr0 + j0 + 16);
        const bf16x8 v10 = *reinterpret_cast<const bf16x8*>(vr1 + j0);
        const bf16x8 v11 = *reinterpret_cast<const bf16x8*>(vr1 + j0 + 16);

        // QK^T (swapped): p[r] = S[key j0+(r&3)+8*(r>>2)+4*hi][q-row q0+lq]
        f32x16 p = {};
        p = __builtin_amdgcn_mfma_f32_32x32x16_bf16(kf[0], qf[0], p, 0, 0, 0);
        p = __builtin_amdgcn_mfma_f32_32x32x16_bf16(kf[1], qf[1], p, 0, 0, 0);
        p = __builtin_amdgcn_mfma_f32_32x32x16_bf16(kf[2], qf[2], p, 0, 0, 0);
        p = __builtin_amdgcn_mfma_f32_32x32x16_bf16(kf[3], qf[3], p, 0, 0, 0);

        // causal mask + exp (no max tracking), lane-local denominator
#pragma unroll
        for (int r = 0; r < 16; ++r) {
            const int key = j0 + (r & 3) + 8 * (r >> 2) + 4 * hi;
            p[r] = (key <= q0 + lq) ? __expf(p[r]) : 0.f;
            lsum += p[r];
        }

        // P-bounce: write packed pairs at C/D key positions (word = key/2)
        pw[2 * hi]      = pk2(p[0],  p[1]);    // keys {4hi+0, 4hi+1}
        pw[2 * hi + 1]  = pk2(p[2],  p[3]);    // keys {4hi+2, 4hi+3}
        pw[4 + 2 * hi]  = pk2(p[4],  p[5]);    // keys {8+4hi, ...}
        pw[5 + 2 * hi]  = pk2(p[6],  p[7]);
        pw[8 + 2 * hi]  = pk2(p[8],  p[9]);    // keys {16+4hi, ...}
        pw[9 + 2 * hi]  = pk2(p[10], p[11]);
        pw[12 + 2 * hi] = pk2(p[12], p[13]);   // keys {24+4hi, ...}
        pw[13 + 2 * hi] = pk2(p[14], p[15]);
        // read back B-frags: lane (lq,hi) takes keys kc*16 + hi*8 + 0..7
        union U8 { bf16x4 half[2]; bf16x8 v; };
        U8 pf0, pf1;
        pf0.half[0] = *reinterpret_cast<const bf16x4*>(prb + hi * 8);
        pf0.half[1] = *reinterpret_cast<const bf16x4*>(prb + hi * 8 + 4);
        pf1.half[0] = *reinterpret_cast<const bf16x4*>(prb + 16 + hi * 8);
        pf1.half[1] = *reinterpret_cast<const bf16x4*>(prb + 16 + hi * 8 + 4);

        // PV: O^T[d][q] += V^T[d][k] * P[k][q]
        o0 = __builtin_amdgcn_mfma_f32_32x32x16_bf16(v00, pf0.v, o0, 0, 0, 0);
        o0 = __builtin_amdgcn_mfma_f32_32x32x16_bf16(v01, pf1.v, o0, 0, 0, 0);
        o1 = __builtin_amdgcn_mfma_f32_32x32x16_bf16(v10, pf0.v, o1, 0, 0, 0);
        o1 = __builtin_amdgcn_mfma_f32_32x32x16_bf16(v11, pf1.v, o1, 0, 0, 0);

#pragma unroll
        for (int dc = 0; dc < 4; ++dc) kf[dc] = nk[dc];
    }

    // split-K combine via LDS (epilogue only; separate region from P-bounce)
    float* my = cmb + ((size_t)w * 64 + lane) * 33;
#pragma unroll
    for (int i = 0; i < 16; ++i) { my[i] = o0[i]; my[16 + i] = o1[i]; }
    my[32] = lsum;
    __syncthreads();
    // wave w reduces output slots [8w, 8w+8) across the 4 waves
    float tot[8] = {};
    float lt = 0.f;
#pragma unroll
    for (int w2 = 0; w2 < 4; ++w2) {
        const float* src = cmb + ((size_t)w2 * 64 + lane) * 33;
#pragma unroll
        for (int j = 0; j < 8; ++j) tot[j] += src[8 * w + j];
        lt += src[32];
    }
    lt += __shfl_xor(lt, 32);        // other key-half of this q-row
    const float inv = 1.0f / lt;
    // slot 8w+j holds d = 32*(w>>1) + 16*(w&1) + 8*(j>>2) + 4*hi + (j&3)
    const int dbase = 32 * (w >> 1) + 16 * (w & 1) + 4 * hi;
    __bf16* cp = ctx + (size_t)(q0 + lq) * DM + h * HD;
    bf16x4 s0, s1;
#pragma unroll
    for (int j = 0; j < 4; ++j) {
        s0[j] = (__bf16)(tot[j] * inv);
        s1[j] = (__bf16)(tot[4 + j] * inv);
    }
    *reinterpret_cast<bf16x4*>(cp + dbase) = s0;
    *reinterpret_cast<bf16x4*>(cp + dbase + 8) = s1;
}

// ---------------------------------------------------------------------------
// All 3 output projections (blockIdx.z = scale). f32 out. 128x128 blocks.
// ---------------------------------------------------------------------------
__global__ __launch_bounds__(256)
void gemm_out_all(const __bf16* __restrict__ c0, const __bf16* __restrict__ c1,
                  const __bf16* __restrict__ c2, const __bf16* __restrict__ Wob,
                  const float* __restrict__ bo, float* __restrict__ out) {
    const __bf16* A; float* o; int M;
    switch (blockIdx.z) {
        case 0:  A = c0; o = out;             M = 2048; break;
        case 1:  A = c1; o = out + 2048 * DM; M = 1024; break;
        default: A = c2; o = out + 3072 * DM; M = 512;  break;
    }
    if ((int)blockIdx.y * 128 >= M) return;
    const int lane = threadIdx.x & 63;
    const int w = threadIdx.x >> 6;
    const int g = lane >> 4, t = lane & 15;
    const int rb = blockIdx.y * 128 + (w >> 1) * 64;
    const int cb = blockIdx.x * 128 + (w & 1) * 64;
    f32x4 acc[4][4] = {};
    gemm_core4x4(A + (size_t)(rb + t) * DM + g * 8, Wob + (size_t)(cb + t) * DM + g * 8, acc);
#pragma unroll
    for (int ni = 0; ni < 4; ++ni) {
        const int col = cb + ni * 16 + t;
        const float bb = bo[col];
#pragma unroll
        for (int mi = 0; mi < 4; ++mi) {
            const int row0 = rb + mi * 16 + g * 4;
#pragma unroll
            for (int r = 0; r < 4; ++r)
                o[(size_t)(row0 + r) * DM + col] = acc[mi][ni][r] + bb;
        }
    }
}

// ---------------------------------------------------------------------------
extern "C" void kernel_launch(void* const* d_in, const int* in_sizes, int n_in,
                              void* d_out, int out_size, void* d_ws, size_t ws_size,
                              hipStream_t stream) {
    const float* x0 = (const float*)d_in[0];
    const float* x1 = (const float*)d_in[1];
    const float* x2 = (const float*)d_in[2];
    const float* Wq = (const float*)d_in[3];
    const float* bq = (const float*)d_in[4];
    const float* Wk = (const float*)d_in[5];
    const float* bk = (const float*)d_in[6];
    const float* Wv = (const float*)d_in[7];
    const float* bv = (const float*)d_in[8];
    const float* Wo = (const float*)d_in[9];
    const float* bo = (const float*)d_in[10];
    float* out = (float*)d_out;

    // bf16 workspace, ~39 MB
    __bf16* xb0 = (__bf16*)d_ws;        // 2M
    __bf16* xb1 = xb0 + 2 * M1;         // 1M
    __bf16* xb2 = xb1 + M1;             // 0.5M
    __bf16* Wqb = xb2 + M1 / 2;         // 3M
    __bf16* Wkb = Wqb + 3 * M1;         // 3M
    __bf16* Wvb = Wkb + 3 * M1;         // 1M
    __bf16* Wob = Wvb + M1;             // 1M
    __bf16* vt0 = Wob + M1;             // 2M
    __bf16* vt1 = vt0 + 2 * M1;         // 1M
    __bf16* vt2 = vt1 + M1;             // 0.5M
    __bf16* qb0 = vt2 + M1 / 2;         // 2M
    __bf16* kb0 = qb0 + 2 * M1;         // 2M
    __bf16* qb1 = kb0 + 2 * M1;         // 1M
    __bf16* kb1 = qb1 + M1;             // 1M
    __bf16* qb2 = kb1 + M1;             // 0.5M
    __bf16* kb2 = qb2 + M1 / 2;         // 0.5M

    // 1. convert everything to bf16
    cvt_all<<<5888, 256, 0, stream>>>(x0, x1, x2, Wq, Wk, Wv, Wo,
                                      xb0, xb1, xb2, Wqb, Wkb, Wvb, Wob);
    // 2. all pre-attention GEMMs (Q-with-rope | K-with-rope | V-with-pool)
    gemm_pre<<<dim3(8, 16, 7), 256, 0, stream>>>(xb0, xb1, xb2, Wqb, Wkb, Wvb,
                                                 bq, bk, bv,
                                                 qb0, kb0, qb1, kb1, qb2, kb2,
                                                 vt0, vt1, vt2);
    // 3. attention, all scales; 32-row waves, split-K, XCD head affinity
    attn_all<<<1792, 256, 0, stream>>>(qb0, kb0, vt0, qb0,
                                       qb1, kb1, vt1, qb1,
                                       qb2, kb2, vt2, qb2);
    // 4. output projections (one launch, 3 jobs), f32 into d_out
    gemm_out_all<<<dim3(8, 16, 3), 256, 0, stream>>>(qb0, qb1, qb2, Wob, bo, out);
}

// Round 11
// 193.462 us; speedup vs baseline: 1.5587x; 1.2626x over previous
//
#include <hip/hip_runtime.h>
#include <hip/hip_bf16.h>
#include <math.h>

typedef __bf16 bf16x8 __attribute__((ext_vector_type(8)));
typedef __bf16 bf16x4 __attribute__((ext_vector_type(4)));
typedef __bf16 bf16x2 __attribute__((ext_vector_type(2)));
typedef float f32x4 __attribute__((ext_vector_type(4)));
typedef float f32x16 __attribute__((ext_vector_type(16)));

static constexpr int DM = 1024;    // d_model
static constexpr int HD = 64;      // head dim
static constexpr size_t M1 = 1024 * 1024;

// pack two f32 -> u32 of two bf16 (compiler emits v_cvt_pk_bf16_f32)
__device__ __forceinline__ unsigned pk2(float a, float b) {
    union { __bf16 h[2]; unsigned u; } t;
    t.h[0] = (__bf16)a; t.h[1] = (__bf16)b;
    return t.u;
}

// async global->LDS, 16 B per lane; LDS dest = wave-uniform base + lane*16
typedef const __attribute__((address_space(1))) unsigned int* gp_t;
typedef __attribute__((address_space(3))) unsigned int* lp_t;
__device__ __forceinline__ void gload_lds16(const void* g, void* l) {
    __builtin_amdgcn_global_load_lds((gp_t)g, (lp_t)l, 16, 0, 0);
}

// ---------------------------------------------------------------------------
// Fused f32->bf16 convert of all 7 tensors, one launch.
// ---------------------------------------------------------------------------
__global__ void cvt_all(const float* __restrict__ x0, const float* __restrict__ x1,
                        const float* __restrict__ x2, const float* __restrict__ Wq,
                        const float* __restrict__ Wk, const float* __restrict__ Wv,
                        const float* __restrict__ Wo,
                        __bf16* __restrict__ xb0, __bf16* __restrict__ xb1,
                        __bf16* __restrict__ xb2, __bf16* __restrict__ Wqb,
                        __bf16* __restrict__ Wkb, __bf16* __restrict__ Wvb,
                        __bf16* __restrict__ Wob) {
    size_t i = (size_t)(blockIdx.x * blockDim.x + threadIdx.x) * 8;
    const float* in; __bf16* outp; size_t off;
    if      (i < 2 * M1)            { in = x0; outp = xb0; off = i; }
    else if (i < 3 * M1)            { in = x1; outp = xb1; off = i - 2 * M1; }
    else if (i < 3 * M1 + M1 / 2)   { in = x2; outp = xb2; off = i - 3 * M1; }
    else if (i < 6 * M1 + M1 / 2)   { in = Wq; outp = Wqb; off = i - (3 * M1 + M1 / 2); }
    else if (i < 9 * M1 + M1 / 2)   { in = Wk; outp = Wkb; off = i - (6 * M1 + M1 / 2); }
    else if (i < 10 * M1 + M1 / 2)  { in = Wv; outp = Wvb; off = i - (9 * M1 + M1 / 2); }
    else if (i < 11 * M1 + M1 / 2)  { in = Wo; outp = Wob; off = i - (10 * M1 + M1 / 2); }
    else return;
    const float4 a = *reinterpret_cast<const float4*>(in + off);
    const float4 b = *reinterpret_cast<const float4*>(in + off + 4);
    bf16x8 r;
    r[0] = (__bf16)a.x; r[1] = (__bf16)a.y; r[2] = (__bf16)a.z; r[3] = (__bf16)a.w;
    r[4] = (__bf16)b.x; r[5] = (__bf16)b.y; r[6] = (__bf16)b.z; r[7] = (__bf16)b.w;
    *reinterpret_cast<bf16x8*>(outp + off) = r;
}

// ---------------------------------------------------------------------------
// m97-structure GEMM core: 128x128 block tile, 4 waves (2x2) of 64x64.
// Per BK=32 K-step: barrier | 4x global_load_lds (A,B tiles, 8 KB each,
// LDS layout [kc 0..3][128 rows][8 bf16] -> 2-way-free ds_read_b128 frags)
// | barrier | 8 ds_read_b128 + 16 MFMA.
// C/D layout: row=(lane>>4)*4+reg, col=lane&15 (m89-verified)
// ---------------------------------------------------------------------------
__device__ __forceinline__ void gemm_lds_core(const __bf16* __restrict__ A,
                                              const __bf16* __restrict__ W,
                                              int rb, int cb, int tix,
                                              __bf16* lA, __bf16* lB,
                                              f32x4 (&acc)[4][4]) {
    const int lane = tix & 63;
    const int w = tix >> 6;
    const int g = lane >> 4, t = lane & 15;
    // staging slots: inst j: s = j*256 + w*64 + lane; kc = s>>7, row = s&127
    const int s0 = w * 64 + lane;
    const int s1 = s0 + 256;
    const __bf16* a0 = A + (size_t)(rb + (s0 & 127)) * DM + (s0 >> 7) * 8;
    const __bf16* a1 = A + (size_t)(rb + (s1 & 127)) * DM + (s1 >> 7) * 8;
    const __bf16* b0 = W + (size_t)(cb + (s0 & 127)) * DM + (s0 >> 7) * 8;
    const __bf16* b1 = W + (size_t)(cb + (s1 & 127)) * DM + (s1 >> 7) * 8;
    __bf16* dA0 = lA + (size_t)(w * 64) * 8;          // wave-uniform LDS bases
    __bf16* dA1 = lA + (size_t)(256 + w * 64) * 8;
    __bf16* dB0 = lB + (size_t)(w * 64) * 8;
    __bf16* dB1 = lB + (size_t)(256 + w * 64) * 8;
    // frag read pointers (constant across K: LDS is reused per step)
    const int rw = (w >> 1) * 64, cw = (w & 1) * 64;
    const __bf16* ra[4]; const __bf16* rbp[4];
#pragma unroll
    for (int i = 0; i < 4; ++i) {
        ra[i]  = lA + (size_t)(g * 128 + rw + i * 16 + t) * 8;
        rbp[i] = lB + (size_t)(g * 128 + cw + i * 16 + t) * 8;
    }
    for (int kk = 0; kk < DM; kk += 32) {
        __syncthreads();                      // previous step's reads complete
        gload_lds16(a0 + kk, dA0);
        gload_lds16(a1 + kk, dA1);
        gload_lds16(b0 + kk, dB0);
        gload_lds16(b1 + kk, dB1);
        __syncthreads();                      // vmcnt(0) drain + barrier
        bf16x8 af[4], bfr[4];
#pragma unroll
        for (int i = 0; i < 4; ++i) {
            af[i]  = *reinterpret_cast<const bf16x8*>(ra[i]);
            bfr[i] = *reinterpret_cast<const bf16x8*>(rbp[i]);
        }
#pragma unroll
        for (int mi = 0; mi < 4; ++mi)
#pragma unroll
            for (int ni = 0; ni < 4; ++ni)
                acc[mi][ni] = __builtin_amdgcn_mfma_f32_16x16x32_bf16(af[mi], bfr[ni], acc[mi][ni], 0, 0, 0);
    }
}

// ---------------------------------------------------------------------------
// All pre-attention GEMMs, flat 1-D grid of 576 blocks (no phantoms):
//   jobs z=0,2,4: Q proj + fused RoPE + 1/8 scale | z=1,3,5: K proj + RoPE
//   z=6: V proj -> transposed vt0 + fused avg-pool into vt1, vt2
// Chunked XCD swizzle: swz=(bid&7)*72+(bid>>3) (576=8*72, bijective);
// within-job column-major enumeration -> co-XCD blocks share W panels.
// ---------------------------------------------------------------------------
__global__ __launch_bounds__(256)
void gemm_pre(const __bf16* __restrict__ xb0, const __bf16* __restrict__ xb1,
              const __bf16* __restrict__ xb2, const __bf16* __restrict__ Wqb,
              const __bf16* __restrict__ Wkb, const __bf16* __restrict__ Wvb,
              const float* __restrict__ bq, const float* __restrict__ bk,
              const float* __restrict__ bv,
              __bf16* __restrict__ qb0, __bf16* __restrict__ kb0,
              __bf16* __restrict__ qb1, __bf16* __restrict__ kb1,
              __bf16* __restrict__ qb2, __bf16* __restrict__ kb2,
              __bf16* __restrict__ vt0, __bf16* __restrict__ vt1,
              __bf16* __restrict__ vt2) {
    __shared__ __align__(16) __bf16 lA[4096], lB[4096];   // 16 KB
    const int bid = blockIdx.x;
    const int swz = (bid & 7) * 72 + (bid >> 3);
    int z, local, mblk;
    if      (swz < 128) { z = 0; local = swz;       mblk = 16; }
    else if (swz < 256) { z = 1; local = swz - 128; mblk = 16; }
    else if (swz < 320) { z = 2; local = swz - 256; mblk = 8;  }
    else if (swz < 384) { z = 3; local = swz - 320; mblk = 8;  }
    else if (swz < 416) { z = 4; local = swz - 384; mblk = 4;  }
    else if (swz < 448) { z = 5; local = swz - 416; mblk = 4;  }
    else                { z = 6; local = swz - 448; mblk = 16; }
    const __bf16* A; const __bf16* W; const float* bias; __bf16* out;
    switch (z) {
        case 0:  A = xb0; W = Wqb;          bias = bq;        out = qb0; break;
        case 1:  A = xb0; W = Wkb;          bias = bk;        out = kb0; break;
        case 2:  A = xb1; W = Wqb + M1;     bias = bq + 1024; out = qb1; break;
        case 3:  A = xb1; W = Wkb + M1;     bias = bk + 1024; out = kb1; break;
        case 4:  A = xb2; W = Wqb + 2 * M1; bias = bq + 2048; out = qb2; break;
        case 5:  A = xb2; W = Wkb + 2 * M1; bias = bk + 2048; out = kb2; break;
        default: A = xb0; W = Wvb;          bias = bv;        out = nullptr; break;
    }
    const int rb = (local % mblk) * 128;
    const int cb = (local / mblk) * 128;
    const int tix = threadIdx.x;
    f32x4 acc[4][4] = {};
    gemm_lds_core(A, W, rb, cb, tix, lA, lB, acc);

    const int lane = tix & 63;
    const int w = tix >> 6;
    const int g = lane >> 4, t = lane & 15;
    const int rbw = rb + (w >> 1) * 64;
    const int cbw = cb + (w & 1) * 64;     // head-aligned 64-col span

    if (z == 6) {
        // V projection epilogue: transposed store + fused avg-pool
#pragma unroll
        for (int ni = 0; ni < 4; ++ni) {
            const int col = cbw + ni * 16 + t;          // d dim
            const float bb = bias[col];
#pragma unroll
            for (int mi = 0; mi < 4; ++mi) {
                const int row0 = rbw + mi * 16 + g * 4; // n dim
                const f32x4 a = acc[mi][ni];
                bf16x4 pk;
#pragma unroll
                for (int r = 0; r < 4; ++r) pk[r] = (__bf16)(a[r] + bb);
                *reinterpret_cast<bf16x4*>(vt0 + (size_t)col * 2048 + row0) = pk;
                bf16x2 p2;
                p2[0] = (__bf16)(0.5f * (a[0] + a[1]) + bb);
                p2[1] = (__bf16)(0.5f * (a[2] + a[3]) + bb);
                *reinterpret_cast<bf16x2*>(vt1 + (size_t)col * 1024 + row0 / 2) = p2;
                vt2[(size_t)col * 512 + row0 / 4] =
                    (__bf16)(0.25f * (a[0] + a[1] + a[2] + a[3]) + bb);
            }
        }
    } else {
        // Q/K epilogue with fused RoPE; Q additionally scaled by 1/8
        const float qmul = (z & 1) ? 1.0f : 0.125f;
        const float ps = (float)(1 << (z >> 1));   // 1,2,4
#pragma unroll
        for (int ni = 0; ni < 2; ++ni) {
            const int j = ni * 16 + t;             // [0,32) within head
            const float invf = __expf(-(float)j * 0.28782313662425576f);
            const float b1 = bias[cbw + j];
            const float b2 = bias[cbw + j + 32];
#pragma unroll
            for (int mi = 0; mi < 4; ++mi) {
#pragma unroll
                for (int r = 0; r < 4; ++r) {
                    const int row = rbw + mi * 16 + g * 4 + r;
                    float c, s;
                    __sincosf((float)row * ps * invf, &s, &c);
                    const float x1 = acc[mi][ni][r] + b1;
                    const float x2 = acc[mi][ni + 2][r] + b2;
                    out[(size_t)row * DM + cbw + j]      = (__bf16)((x1 * c - x2 * s) * qmul);
                    out[(size_t)row * DM + cbw + j + 32] = (__bf16)((x1 * s + x2 * c) * qmul);
                }
            }
        }
    }
}

// ---------------------------------------------------------------------------
// MFMA flash attention v6 (unchanged from round 10): 32-row waves, swapped
// QK^T, lane-local softmax, per-wave LDS P-bounce, split-K, XCD affinity.
// ---------------------------------------------------------------------------
__global__ __launch_bounds__(256)
void attn_all(const __bf16* __restrict__ qb0, const __bf16* __restrict__ kb0,
              const __bf16* __restrict__ vt0, __bf16* __restrict__ ctx0,
              const __bf16* __restrict__ qb1, const __bf16* __restrict__ kb1,
              const __bf16* __restrict__ vt1, __bf16* __restrict__ ctx1,
              const __bf16* __restrict__ qb2, const __bf16* __restrict__ kb2,
              const __bf16* __restrict__ vt2, __bf16* __restrict__ ctx2) {
    __shared__ __align__(16) unsigned pb[4 * 32 * 18];  // P bounce (per-wave)
    __shared__ __align__(16) float cmb[4 * 64 * 33];    // split-K combine
    const int bid = blockIdx.x;
    const int job = (bid & 7) * 224 + (bid >> 3);
    const int h = job / 112;
    int rem = job % 112;
    const __bf16 *qb, *kb, *vt; __bf16* ctx; int N, nq;
    if (rem < 64)      { qb = qb0; kb = kb0; vt = vt0; ctx = ctx0; N = 2048; nq = 64; }
    else if (rem < 96) { rem -= 64; qb = qb1; kb = kb1; vt = vt1; ctx = ctx1; N = 1024; nq = 32; }
    else               { rem -= 96; qb = qb2; kb = kb2; vt = vt2; ctx = ctx2; N = 512;  nq = 16; }
    const int qt = (rem & 1) ? (nq - 1 - (rem >> 1)) : (rem >> 1);
    const int lane = threadIdx.x & 63;
    const int w = threadIdx.x >> 6;
    const int q0 = qt * 32;
    const int lq = lane & 31;
    const int hi = lane >> 5;

    const __bf16* qp = qb + (size_t)(q0 + lq) * DM + h * HD + hi * 8;
    bf16x8 qf[4];
#pragma unroll
    for (int dc = 0; dc < 4; ++dc)
        qf[dc] = *reinterpret_cast<const bf16x8*>(qp + dc * 16);

    f32x16 o0 = {}, o1 = {};
    float lsum = 0.f;

    const __bf16* kbase = kb + h * HD + hi * 8;
    const __bf16* vr0 = vt + ((size_t)(h * HD + lq)) * N + hi * 8;
    const __bf16* vr1 = vt + ((size_t)(h * HD + 32 + lq)) * N + hi * 8;
    const int ktiles = qt + 1;

    unsigned* pw = pb + (w * 32 + lq) * 18;
    const __bf16* prb = (const __bf16*)pw;

    bf16x8 kf[4];
    {
        const __bf16* kp = kbase + (size_t)(w * 32 + lq) * DM;
#pragma unroll
        for (int dc = 0; dc < 4; ++dc)
            kf[dc] = *reinterpret_cast<const bf16x8*>(kp + dc * 16);
    }

    for (int kt = w; kt < ktiles; kt += 4) {
        const int j0 = kt * 32;
        const int jn = (kt + 4 < ktiles) ? j0 + 128 : j0;
        bf16x8 nk[4];
        {
            const __bf16* kp = kbase + (size_t)(jn + lq) * DM;
#pragma unroll
            for (int dc = 0; dc < 4; ++dc)
                nk[dc] = *reinterpret_cast<const bf16x8*>(kp + dc * 16);
        }
        const bf16x8 v00 = *reinterpret_cast<const bf16x8*>(vr0 + j0);
        const bf16x8 v01 = *reinterpret_cast<const bf16x8*>(vr0 + j0 + 16);
        const bf16x8 v10 = *reinterpret_cast<const bf16x8*>(vr1 + j0);
        const bf16x8 v11 = *reinterpret_cast<const bf16x8*>(vr1 + j0 + 16);

        f32x16 p = {};
        p = __builtin_amdgcn_mfma_f32_32x32x16_bf16(kf[0], qf[0], p, 0, 0, 0);
        p = __builtin_amdgcn_mfma_f32_32x32x16_bf16(kf[1], qf[1], p, 0, 0, 0);
        p = __builtin_amdgcn_mfma_f32_32x32x16_bf16(kf[2], qf[2], p, 0, 0, 0);
        p = __builtin_amdgcn_mfma_f32_32x32x16_bf16(kf[3], qf[3], p, 0, 0, 0);

#pragma unroll
        for (int r = 0; r < 16; ++r) {
            const int key = j0 + (r & 3) + 8 * (r >> 2) + 4 * hi;
            p[r] = (key <= q0 + lq) ? __expf(p[r]) : 0.f;
            lsum += p[r];
        }

        pw[2 * hi]      = pk2(p[0],  p[1]);
        pw[2 * hi + 1]  = pk2(p[2],  p[3]);
        pw[4 + 2 * hi]  = pk2(p[4],  p[5]);
        pw[5 + 2 * hi]  = pk2(p[6],  p[7]);
        pw[8 + 2 * hi]  = pk2(p[8],  p[9]);
        pw[9 + 2 * hi]  = pk2(p[10], p[11]);
        pw[12 + 2 * hi] = pk2(p[12], p[13]);
        pw[13 + 2 * hi] = pk2(p[14], p[15]);
        union U8 { bf16x4 half[2]; bf16x8 v; };
        U8 pf0, pf1;
        pf0.half[0] = *reinterpret_cast<const bf16x4*>(prb + hi * 8);
        pf0.half[1] = *reinterpret_cast<const bf16x4*>(prb + hi * 8 + 4);
        pf1.half[0] = *reinterpret_cast<const bf16x4*>(prb + 16 + hi * 8);
        pf1.half[1] = *reinterpret_cast<const bf16x4*>(prb + 16 + hi * 8 + 4);

        o0 = __builtin_amdgcn_mfma_f32_32x32x16_bf16(v00, pf0.v, o0, 0, 0, 0);
        o0 = __builtin_amdgcn_mfma_f32_32x32x16_bf16(v01, pf1.v, o0, 0, 0, 0);
        o1 = __builtin_amdgcn_mfma_f32_32x32x16_bf16(v10, pf0.v, o1, 0, 0, 0);
        o1 = __builtin_amdgcn_mfma_f32_32x32x16_bf16(v11, pf1.v, o1, 0, 0, 0);

#pragma unroll
        for (int dc = 0; dc < 4; ++dc) kf[dc] = nk[dc];
    }

    float* my = cmb + ((size_t)w * 64 + lane) * 33;
#pragma unroll
    for (int i = 0; i < 16; ++i) { my[i] = o0[i]; my[16 + i] = o1[i]; }
    my[32] = lsum;
    __syncthreads();
    float tot[8] = {};
    float lt = 0.f;
#pragma unroll
    for (int w2 = 0; w2 < 4; ++w2) {
        const float* src = cmb + ((size_t)w2 * 64 + lane) * 33;
#pragma unroll
        for (int j = 0; j < 8; ++j) tot[j] += src[8 * w + j];
        lt += src[32];
    }
    lt += __shfl_xor(lt, 32);
    const float inv = 1.0f / lt;
    const int dbase = 32 * (w >> 1) + 16 * (w & 1) + 4 * hi;
    __bf16* cp = ctx + (size_t)(q0 + lq) * DM + h * HD;
    bf16x4 s0, s1;
#pragma unroll
    for (int j = 0; j < 4; ++j) {
        s0[j] = (__bf16)(tot[j] * inv);
        s1[j] = (__bf16)(tot[4 + j] * inv);
    }
    *reinterpret_cast<bf16x4*>(cp + dbase) = s0;
    *reinterpret_cast<bf16x4*>(cp + dbase + 8) = s1;
}

// ---------------------------------------------------------------------------
// Output projections, flat grid of 224 blocks (8x28 chunked XCD swizzle).
// ---------------------------------------------------------------------------
__global__ __launch_bounds__(256)
void gemm_out_all(const __bf16* __restrict__ c0, const __bf16* __restrict__ c1,
                  const __bf16* __restrict__ c2, const __bf16* __restrict__ Wob,
                  const float* __restrict__ bo, float* __restrict__ out) {
    __shared__ __align__(16) __bf16 lA[4096], lB[4096];
    const int bid = blockIdx.x;
    const int swz = (bid & 7) * 28 + (bid >> 3);     // 224 = 8*28
    int z, local, mblk;
    if      (swz < 128) { z = 0; local = swz;       mblk = 16; }
    else if (swz < 192) { z = 1; local = swz - 128; mblk = 8;  }
    else                { z = 2; local = swz - 192; mblk = 4;  }
    const __bf16* A; float* o;
    switch (z) {
        case 0:  A = c0; o = out;             break;
        case 1:  A = c1; o = out + 2048 * DM; break;
        default: A = c2; o = out + 3072 * DM; break;
    }
    const int rb = (local % mblk) * 128;
    const int cb = (local / mblk) * 128;
    const int tix = threadIdx.x;
    f32x4 acc[4][4] = {};
    gemm_lds_core(A, Wob, rb, cb, tix, lA, lB, acc);

    const int lane = tix & 63;
    const int w = tix >> 6;
    const int g = lane >> 4, t = lane & 15;
    const int rbw = rb + (w >> 1) * 64;
    const int cbw = cb + (w & 1) * 64;
#pragma unroll
    for (int ni = 0; ni < 4; ++ni) {
        const int col = cbw + ni * 16 + t;
        const float bb = bo[col];
#pragma unroll
        for (int mi = 0; mi < 4; ++mi) {
            const int row0 = rbw + mi * 16 + g * 4;
#pragma unroll
            for (int r = 0; r < 4; ++r)
                o[(size_t)(row0 + r) * DM + col] = acc[mi][ni][r] + bb;
        }
    }
}

// ---------------------------------------------------------------------------
extern "C" void kernel_launch(void* const* d_in, const int* in_sizes, int n_in,
                              void* d_out, int out_size, void* d_ws, size_t ws_size,
                              hipStream_t stream) {
    const float* x0 = (const float*)d_in[0];
    const float* x1 = (const float*)d_in[1];
    const float* x2 = (const float*)d_in[2];
    const float* Wq = (const float*)d_in[3];
    const float* bq = (const float*)d_in[4];
    const float* Wk = (const float*)d_in[5];
    const float* bk = (const float*)d_in[6];
    const float* Wv = (const float*)d_in[7];
    const float* bv = (const float*)d_in[8];
    const float* Wo = (const float*)d_in[9];
    const float* bo = (const float*)d_in[10];
    float* out = (float*)d_out;

    // bf16 workspace, ~39 MB
    __bf16* xb0 = (__bf16*)d_ws;        // 2M
    __bf16* xb1 = xb0 + 2 * M1;         // 1M
    __bf16* xb2 = xb1 + M1;             // 0.5M
    __bf16* Wqb = xb2 + M1 / 2;         // 3M
    __bf16* Wkb = Wqb + 3 * M1;         // 3M
    __bf16* Wvb = Wkb + 3 * M1;         // 1M
    __bf16* Wob = Wvb + M1;             // 1M
    __bf16* vt0 = Wob + M1;             // 2M
    __bf16* vt1 = vt0 + 2 * M1;         // 1M
    __bf16* vt2 = vt1 + M1;             // 0.5M
    __bf16* qb0 = vt2 + M1 / 2;         // 2M
    __bf16* kb0 = qb0 + 2 * M1;         // 2M
    __bf16* qb1 = kb0 + 2 * M1;         // 1M
    __bf16* kb1 = qb1 + M1;             // 1M
    __bf16* qb2 = kb1 + M1;             // 0.5M
    __bf16* kb2 = qb2 + M1 / 2;         // 0.5M

    // 1. convert everything to bf16
    cvt_all<<<5888, 256, 0, stream>>>(x0, x1, x2, Wq, Wk, Wv, Wo,
                                      xb0, xb1, xb2, Wqb, Wkb, Wvb, Wob);
    // 2. all pre-attention GEMMs (flat grid, LDS-staged core, XCD chunked)
    gemm_pre<<<576, 256, 0, stream>>>(xb0, xb1, xb2, Wqb, Wkb, Wvb,
                                      bq, bk, bv,
                                      qb0, kb0, qb1, kb1, qb2, kb2,
                                      vt0, vt1, vt2);
    // 3. attention, all scales; 32-row waves, split-K, XCD head affinity
    attn_all<<<1792, 256, 0, stream>>>(qb0, kb0, vt0, qb0,
                                       qb1, kb1, vt1, qb1,
                                       qb2, kb2, vt2, qb2);
    // 4. output projections (flat grid, LDS-staged core), f32 into d_out
    gemm_out_all<<<224, 256, 0, stream>>>(qb0, qb1, qb2, Wob, bo, out);
}

// Round 12
// 190.597 us; speedup vs baseline: 1.5821x; 1.0150x over previous
//
#include <hip/hip_runtime.h>
#include <hip/hip_bf16.h>
#include <math.h>

typedef __bf16 bf16x8 __attribute__((ext_vector_type(8)));
typedef __bf16 bf16x4 __attribute__((ext_vector_type(4)));
typedef __bf16 bf16x2 __attribute__((ext_vector_type(2)));
typedef float f32x4 __attribute__((ext_vector_type(4)));
typedef float f32x16 __attribute__((ext_vector_type(16)));

static constexpr int DM = 1024;    // d_model
static constexpr int HD = 64;      // head dim
static constexpr size_t M1 = 1024 * 1024;

// pack two f32 -> u32 of two bf16 (compiler emits v_cvt_pk_bf16_f32)
__device__ __forceinline__ unsigned pk2(float a, float b) {
    union { __bf16 h[2]; unsigned u; } t;
    t.h[0] = (__bf16)a; t.h[1] = (__bf16)b;
    return t.u;
}

// async global->LDS, 16 B per lane; LDS dest = wave-uniform base + lane*16
typedef const __attribute__((address_space(1))) unsigned int* gp_t;
typedef __attribute__((address_space(3))) unsigned int* lp_t;
__device__ __forceinline__ void gload_lds16(const void* g, void* l) {
    __builtin_amdgcn_global_load_lds((gp_t)g, (lp_t)l, 16, 0, 0);
}

// ---------------------------------------------------------------------------
// Fused f32->bf16 convert of all 7 tensors, one launch.
// ---------------------------------------------------------------------------
__global__ void cvt_all(const float* __restrict__ x0, const float* __restrict__ x1,
                        const float* __restrict__ x2, const float* __restrict__ Wq,
                        const float* __restrict__ Wk, const float* __restrict__ Wv,
                        const float* __restrict__ Wo,
                        __bf16* __restrict__ xb0, __bf16* __restrict__ xb1,
                        __bf16* __restrict__ xb2, __bf16* __restrict__ Wqb,
                        __bf16* __restrict__ Wkb, __bf16* __restrict__ Wvb,
                        __bf16* __restrict__ Wob) {
    size_t i = (size_t)(blockIdx.x * blockDim.x + threadIdx.x) * 8;
    const float* in; __bf16* outp; size_t off;
    if      (i < 2 * M1)            { in = x0; outp = xb0; off = i; }
    else if (i < 3 * M1)            { in = x1; outp = xb1; off = i - 2 * M1; }
    else if (i < 3 * M1 + M1 / 2)   { in = x2; outp = xb2; off = i - 3 * M1; }
    else if (i < 6 * M1 + M1 / 2)   { in = Wq; outp = Wqb; off = i - (3 * M1 + M1 / 2); }
    else if (i < 9 * M1 + M1 / 2)   { in = Wk; outp = Wkb; off = i - (6 * M1 + M1 / 2); }
    else if (i < 10 * M1 + M1 / 2)  { in = Wv; outp = Wvb; off = i - (9 * M1 + M1 / 2); }
    else if (i < 11 * M1 + M1 / 2)  { in = Wo; outp = Wob; off = i - (10 * M1 + M1 / 2); }
    else return;
    const float4 a = *reinterpret_cast<const float4*>(in + off);
    const float4 b = *reinterpret_cast<const float4*>(in + off + 4);
    bf16x8 r;
    r[0] = (__bf16)a.x; r[1] = (__bf16)a.y; r[2] = (__bf16)a.z; r[3] = (__bf16)a.w;
    r[4] = (__bf16)b.x; r[5] = (__bf16)b.y; r[6] = (__bf16)b.z; r[7] = (__bf16)b.w;
    *reinterpret_cast<bf16x8*>(outp + off) = r;
}

// ---------------------------------------------------------------------------
// GEMM core v2: 128x128 block tile, 4 waves (2x2) of 64x64, BK=32,
// DOUBLE-BUFFERED LDS (T3 minimal 2-phase): stage step k+1 into buf^1,
// then ds_read+MFMA on buf, ONE __syncthreads per step (its vmcnt(0) drain
// lands ~200+ cyc after issue, overlapped with compute).
// LDS per buffer: [kc 0..3][128 rows][8 bf16] per operand (8 KB).
// C/D layout: row=(lane>>4)*4+reg, col=lane&15 (m89-verified)
// ---------------------------------------------------------------------------
__device__ __forceinline__ void gemm_lds_core(const __bf16* __restrict__ A,
                                              const __bf16* __restrict__ W,
                                              int rb, int cb, int tix,
                                              __bf16* lA, __bf16* lB,
                                              f32x4 (&acc)[4][4]) {
    const int lane = tix & 63;
    const int w = tix >> 6;
    const int g = lane >> 4, t = lane & 15;
    // staging slots: inst j: s = j*256 + tix; kc = s>>7, row = s&127
    const int s0 = tix;
    const int s1 = tix + 256;
    const __bf16* a0 = A + (size_t)(rb + (s0 & 127)) * DM + (s0 >> 7) * 8;
    const __bf16* a1 = A + (size_t)(rb + (s1 & 127)) * DM + (s1 >> 7) * 8;
    const __bf16* b0 = W + (size_t)(cb + (s0 & 127)) * DM + (s0 >> 7) * 8;
    const __bf16* b1 = W + (size_t)(cb + (s1 & 127)) * DM + (s1 >> 7) * 8;
    const int rw = (w >> 1) * 64, cw = (w & 1) * 64;

    // prologue: stage step 0 into buffer 0
    gload_lds16(a0, lA + (size_t)(w * 64) * 8);
    gload_lds16(a1, lA + (size_t)(256 + w * 64) * 8);
    gload_lds16(b0, lB + (size_t)(w * 64) * 8);
    gload_lds16(b1, lB + (size_t)(256 + w * 64) * 8);
    __syncthreads();

    int cur = 0;
    for (int kk = 0; kk < DM; kk += 32) {
        // issue next step's staging into the other buffer (async)
        if (kk + 32 < DM) {
            __bf16* nA = lA + (cur ^ 1) * 4096;
            __bf16* nB = lB + (cur ^ 1) * 4096;
            gload_lds16(a0 + kk + 32, nA + (size_t)(w * 64) * 8);
            gload_lds16(a1 + kk + 32, nA + (size_t)(256 + w * 64) * 8);
            gload_lds16(b0 + kk + 32, nB + (size_t)(w * 64) * 8);
            gload_lds16(b1 + kk + 32, nB + (size_t)(256 + w * 64) * 8);
        }
        const __bf16* bA = lA + cur * 4096;
        const __bf16* bB = lB + cur * 4096;
        bf16x8 af[4], bfr[4];
#pragma unroll
        for (int i = 0; i < 4; ++i) {
            af[i]  = *reinterpret_cast<const bf16x8*>(bA + (size_t)(g * 128 + rw + i * 16 + t) * 8);
            bfr[i] = *reinterpret_cast<const bf16x8*>(bB + (size_t)(g * 128 + cw + i * 16 + t) * 8);
        }
#pragma unroll
        for (int mi = 0; mi < 4; ++mi)
#pragma unroll
            for (int ni = 0; ni < 4; ++ni)
                acc[mi][ni] = __builtin_amdgcn_mfma_f32_16x16x32_bf16(af[mi], bfr[ni], acc[mi][ni], 0, 0, 0);
        __syncthreads();    // drains next-step loads (issued ~200 cyc ago) + read fence
        cur ^= 1;
    }
}

// ---------------------------------------------------------------------------
// All pre-attention GEMMs, flat 1-D grid of 576 blocks:
//   jobs z=0,2,4: Q proj + fused RoPE + 1/8 scale | z=1,3,5: K proj + RoPE
//   z=6: V proj -> transposed vt0 + fused avg-pool into vt1, vt2
// Chunked XCD swizzle: swz=(bid&7)*72+(bid>>3) (576=8*72, bijective);
// within-job column-major enumeration -> co-XCD blocks share W panels.
// ---------------------------------------------------------------------------
__global__ __launch_bounds__(256)
void gemm_pre(const __bf16* __restrict__ xb0, const __bf16* __restrict__ xb1,
              const __bf16* __restrict__ xb2, const __bf16* __restrict__ Wqb,
              const __bf16* __restrict__ Wkb, const __bf16* __restrict__ Wvb,
              const float* __restrict__ bq, const float* __restrict__ bk,
              const float* __restrict__ bv,
              __bf16* __restrict__ qb0, __bf16* __restrict__ kb0,
              __bf16* __restrict__ qb1, __bf16* __restrict__ kb1,
              __bf16* __restrict__ qb2, __bf16* __restrict__ kb2,
              __bf16* __restrict__ vt0, __bf16* __restrict__ vt1,
              __bf16* __restrict__ vt2) {
    __shared__ __align__(16) __bf16 lA[8192], lB[8192];   // 32 KB (2 buffers)
    const int bid = blockIdx.x;
    const int swz = (bid & 7) * 72 + (bid >> 3);
    int z, local, mblk;
    if      (swz < 128) { z = 0; local = swz;       mblk = 16; }
    else if (swz < 256) { z = 1; local = swz - 128; mblk = 16; }
    else if (swz < 320) { z = 2; local = swz - 256; mblk = 8;  }
    else if (swz < 384) { z = 3; local = swz - 320; mblk = 8;  }
    else if (swz < 416) { z = 4; local = swz - 384; mblk = 4;  }
    else if (swz < 448) { z = 5; local = swz - 416; mblk = 4;  }
    else                { z = 6; local = swz - 448; mblk = 16; }
    const __bf16* A; const __bf16* W; const float* bias; __bf16* out;
    switch (z) {
        case 0:  A = xb0; W = Wqb;          bias = bq;        out = qb0; break;
        case 1:  A = xb0; W = Wkb;          bias = bk;        out = kb0; break;
        case 2:  A = xb1; W = Wqb + M1;     bias = bq + 1024; out = qb1; break;
        case 3:  A = xb1; W = Wkb + M1;     bias = bk + 1024; out = kb1; break;
        case 4:  A = xb2; W = Wqb + 2 * M1; bias = bq + 2048; out = qb2; break;
        case 5:  A = xb2; W = Wkb + 2 * M1; bias = bk + 2048; out = kb2; break;
        default: A = xb0; W = Wvb;          bias = bv;        out = nullptr; break;
    }
    const int rb = (local % mblk) * 128;
    const int cb = (local / mblk) * 128;
    const int tix = threadIdx.x;
    f32x4 acc[4][4] = {};
    gemm_lds_core(A, W, rb, cb, tix, lA, lB, acc);

    const int lane = tix & 63;
    const int w = tix >> 6;
    const int g = lane >> 4, t = lane & 15;
    const int rbw = rb + (w >> 1) * 64;
    const int cbw = cb + (w & 1) * 64;     // head-aligned 64-col span

    if (z == 6) {
        // V projection epilogue: transposed store + fused avg-pool
#pragma unroll
        for (int ni = 0; ni < 4; ++ni) {
            const int col = cbw + ni * 16 + t;          // d dim
            const float bb = bias[col];
#pragma unroll
            for (int mi = 0; mi < 4; ++mi) {
                const int row0 = rbw + mi * 16 + g * 4; // n dim
                const f32x4 a = acc[mi][ni];
                bf16x4 pk;
#pragma unroll
                for (int r = 0; r < 4; ++r) pk[r] = (__bf16)(a[r] + bb);
                *reinterpret_cast<bf16x4*>(vt0 + (size_t)col * 2048 + row0) = pk;
                bf16x2 p2;
                p2[0] = (__bf16)(0.5f * (a[0] + a[1]) + bb);
                p2[1] = (__bf16)(0.5f * (a[2] + a[3]) + bb);
                *reinterpret_cast<bf16x2*>(vt1 + (size_t)col * 1024 + row0 / 2) = p2;
                vt2[(size_t)col * 512 + row0 / 4] =
                    (__bf16)(0.25f * (a[0] + a[1] + a[2] + a[3]) + bb);
            }
        }
    } else {
        // Q/K epilogue with fused RoPE; Q additionally scaled by 1/8
        const float qmul = (z & 1) ? 1.0f : 0.125f;
        const float ps = (float)(1 << (z >> 1));   // 1,2,4
#pragma unroll
        for (int ni = 0; ni < 2; ++ni) {
            const int j = ni * 16 + t;             // [0,32) within head
            const float invf = __expf(-(float)j * 0.28782313662425576f);
            const float b1 = bias[cbw + j];
            const float b2 = bias[cbw + j + 32];
#pragma unroll
            for (int mi = 0; mi < 4; ++mi) {
#pragma unroll
                for (int r = 0; r < 4; ++r) {
                    const int row = rbw + mi * 16 + g * 4 + r;
                    float c, s;
                    __sincosf((float)row * ps * invf, &s, &c);
                    const float x1 = acc[mi][ni][r] + b1;
                    const float x2 = acc[mi][ni + 2][r] + b2;
                    out[(size_t)row * DM + cbw + j]      = (__bf16)((x1 * c - x2 * s) * qmul);
                    out[(size_t)row * DM + cbw + j + 32] = (__bf16)((x1 * s + x2 * c) * qmul);
                }
            }
        }
    }
}

// ---------------------------------------------------------------------------
// MFMA flash attention v6.1: 32-row waves, swapped QK^T, lane-local softmax,
// per-wave LDS P-bounce, split-K combine. P-bounce and combine regions are
// OVERLAID in one 33.8 KB buffer (43->34 KB => 4 blocks/CU): a block-wide
// __syncthreads after the loop makes the P-bounce region dead before the
// combine writes begin.
// XCD affinity: 1792 blocks = 8 x 224; job=(bid&7)*224+(bid>>3); 2 heads/XCD.
// ---------------------------------------------------------------------------
__global__ __launch_bounds__(256)
void attn_all(const __bf16* __restrict__ qb0, const __bf16* __restrict__ kb0,
              const __bf16* __restrict__ vt0, __bf16* __restrict__ ctx0,
              const __bf16* __restrict__ qb1, const __bf16* __restrict__ kb1,
              const __bf16* __restrict__ vt1, __bf16* __restrict__ ctx1,
              const __bf16* __restrict__ qb2, const __bf16* __restrict__ kb2,
              const __bf16* __restrict__ vt2, __bf16* __restrict__ ctx2) {
    __shared__ __align__(16) float shm[4 * 64 * 33];    // 33.8 KB, overlaid
    unsigned* pb = (unsigned*)shm;                      // loop-phase P-bounce
    float* cmb = shm;                                   // epilogue combine
    const int bid = blockIdx.x;
    const int job = (bid & 7) * 224 + (bid >> 3);
    const int h = job / 112;
    int rem = job % 112;
    const __bf16 *qb, *kb, *vt; __bf16* ctx; int N, nq;
    if (rem < 64)      { qb = qb0; kb = kb0; vt = vt0; ctx = ctx0; N = 2048; nq = 64; }
    else if (rem < 96) { rem -= 64; qb = qb1; kb = kb1; vt = vt1; ctx = ctx1; N = 1024; nq = 32; }
    else               { rem -= 96; qb = qb2; kb = kb2; vt = vt2; ctx = ctx2; N = 512;  nq = 16; }
    const int qt = (rem & 1) ? (nq - 1 - (rem >> 1)) : (rem >> 1);
    const int lane = threadIdx.x & 63;
    const int w = threadIdx.x >> 6;
    const int q0 = qt * 32;
    const int lq = lane & 31;
    const int hi = lane >> 5;

    const __bf16* qp = qb + (size_t)(q0 + lq) * DM + h * HD + hi * 8;
    bf16x8 qf[4];
#pragma unroll
    for (int dc = 0; dc < 4; ++dc)
        qf[dc] = *reinterpret_cast<const bf16x8*>(qp + dc * 16);

    f32x16 o0 = {}, o1 = {};
    float lsum = 0.f;

    const __bf16* kbase = kb + h * HD + hi * 8;
    const __bf16* vr0 = vt + ((size_t)(h * HD + lq)) * N + hi * 8;
    const __bf16* vr1 = vt + ((size_t)(h * HD + 32 + lq)) * N + hi * 8;
    const int ktiles = qt + 1;

    unsigned* pw = pb + (w * 32 + lq) * 18;
    const __bf16* prb = (const __bf16*)pw;

    bf16x8 kf[4];
    {
        const __bf16* kp = kbase + (size_t)(w * 32 + lq) * DM;
#pragma unroll
        for (int dc = 0; dc < 4; ++dc)
            kf[dc] = *reinterpret_cast<const bf16x8*>(kp + dc * 16);
    }

    for (int kt = w; kt < ktiles; kt += 4) {
        const int j0 = kt * 32;
        const int jn = (kt + 4 < ktiles) ? j0 + 128 : j0;
        bf16x8 nk[4];
        {
            const __bf16* kp = kbase + (size_t)(jn + lq) * DM;
#pragma unroll
            for (int dc = 0; dc < 4; ++dc)
                nk[dc] = *reinterpret_cast<const bf16x8*>(kp + dc * 16);
        }
        const bf16x8 v00 = *reinterpret_cast<const bf16x8*>(vr0 + j0);
        const bf16x8 v01 = *reinterpret_cast<const bf16x8*>(vr0 + j0 + 16);
        const bf16x8 v10 = *reinterpret_cast<const bf16x8*>(vr1 + j0);
        const bf16x8 v11 = *reinterpret_cast<const bf16x8*>(vr1 + j0 + 16);

        f32x16 p = {};
        p = __builtin_amdgcn_mfma_f32_32x32x16_bf16(kf[0], qf[0], p, 0, 0, 0);
        p = __builtin_amdgcn_mfma_f32_32x32x16_bf16(kf[1], qf[1], p, 0, 0, 0);
        p = __builtin_amdgcn_mfma_f32_32x32x16_bf16(kf[2], qf[2], p, 0, 0, 0);
        p = __builtin_amdgcn_mfma_f32_32x32x16_bf16(kf[3], qf[3], p, 0, 0, 0);

#pragma unroll
        for (int r = 0; r < 16; ++r) {
            const int key = j0 + (r & 3) + 8 * (r >> 2) + 4 * hi;
            p[r] = (key <= q0 + lq) ? __expf(p[r]) : 0.f;
            lsum += p[r];
        }

        pw[2 * hi]      = pk2(p[0],  p[1]);
        pw[2 * hi + 1]  = pk2(p[2],  p[3]);
        pw[4 + 2 * hi]  = pk2(p[4],  p[5]);
        pw[5 + 2 * hi]  = pk2(p[6],  p[7]);
        pw[8 + 2 * hi]  = pk2(p[8],  p[9]);
        pw[9 + 2 * hi]  = pk2(p[10], p[11]);
        pw[12 + 2 * hi] = pk2(p[12], p[13]);
        pw[13 + 2 * hi] = pk2(p[14], p[15]);
        union U8 { bf16x4 half[2]; bf16x8 v; };
        U8 pf0, pf1;
        pf0.half[0] = *reinterpret_cast<const bf16x4*>(prb + hi * 8);
        pf0.half[1] = *reinterpret_cast<const bf16x4*>(prb + hi * 8 + 4);
        pf1.half[0] = *reinterpret_cast<const bf16x4*>(prb + 16 + hi * 8);
        pf1.half[1] = *reinterpret_cast<const bf16x4*>(prb + 16 + hi * 8 + 4);

        o0 = __builtin_amdgcn_mfma_f32_32x32x16_bf16(v00, pf0.v, o0, 0, 0, 0);
        o0 = __builtin_amdgcn_mfma_f32_32x32x16_bf16(v01, pf1.v, o0, 0, 0, 0);
        o1 = __builtin_amdgcn_mfma_f32_32x32x16_bf16(v10, pf0.v, o1, 0, 0, 0);
        o1 = __builtin_amdgcn_mfma_f32_32x32x16_bf16(v11, pf1.v, o1, 0, 0, 0);

#pragma unroll
        for (int dc = 0; dc < 4; ++dc) kf[dc] = nk[dc];
    }

    __syncthreads();   // all waves done with P-bounce region -> safe to overlay
    float* my = cmb + ((size_t)w * 64 + lane) * 33;
#pragma unroll
    for (int i = 0; i < 16; ++i) { my[i] = o0[i]; my[16 + i] = o1[i]; }
    my[32] = lsum;
    __syncthreads();
    float tot[8] = {};
    float lt = 0.f;
#pragma unroll
    for (int w2 = 0; w2 < 4; ++w2) {
        const float* src = cmb + ((size_t)w2 * 64 + lane) * 33;
#pragma unroll
        for (int j = 0; j < 8; ++j) tot[j] += src[8 * w + j];
        lt += src[32];
    }
    lt += __shfl_xor(lt, 32);
    const float inv = 1.0f / lt;
    const int dbase = 32 * (w >> 1) + 16 * (w & 1) + 4 * hi;
    __bf16* cp = ctx + (size_t)(q0 + lq) * DM + h * HD;
    bf16x4 s0, s1;
#pragma unroll
    for (int j = 0; j < 4; ++j) {
        s0[j] = (__bf16)(tot[j] * inv);
        s1[j] = (__bf16)(tot[4 + j] * inv);
    }
    *reinterpret_cast<bf16x4*>(cp + dbase) = s0;
    *reinterpret_cast<bf16x4*>(cp + dbase + 8) = s1;
}

// ---------------------------------------------------------------------------
// Output projections, flat grid of 224 blocks (8x28 chunked XCD swizzle).
// ---------------------------------------------------------------------------
__global__ __launch_bounds__(256)
void gemm_out_all(const __bf16* __restrict__ c0, const __bf16* __restrict__ c1,
                  const __bf16* __restrict__ c2, const __bf16* __restrict__ Wob,
                  const float* __restrict__ bo, float* __restrict__ out) {
    __shared__ __align__(16) __bf16 lA[8192], lB[8192];
    const int bid = blockIdx.x;
    const int swz = (bid & 7) * 28 + (bid >> 3);     // 224 = 8*28
    int z, local, mblk;
    if      (swz < 128) { z = 0; local = swz;       mblk = 16; }
    else if (swz < 192) { z = 1; local = swz - 128; mblk = 8;  }
    else                { z = 2; local = swz - 192; mblk = 4;  }
    const __bf16* A; float* o;
    switch (z) {
        case 0:  A = c0; o = out;             break;
        case 1:  A = c1; o = out + 2048 * DM; break;
        default: A = c2; o = out + 3072 * DM; break;
    }
    const int rb = (local % mblk) * 128;
    const int cb = (local / mblk) * 128;
    const int tix = threadIdx.x;
    f32x4 acc[4][4] = {};
    gemm_lds_core(A, Wob, rb, cb, tix, lA, lB, acc);

    const int lane = tix & 63;
    const int w = tix >> 6;
    const int g = lane >> 4, t = lane & 15;
    const int rbw = rb + (w >> 1) * 64;
    const int cbw = cb + (w & 1) * 64;
#pragma unroll
    for (int ni = 0; ni < 4; ++ni) {
        const int col = cbw + ni * 16 + t;
        const float bb = bo[col];
#pragma unroll
        for (int mi = 0; mi < 4; ++mi) {
            const int row0 = rbw + mi * 16 + g * 4;
#pragma unroll
            for (int r = 0; r < 4; ++r)
                o[(size_t)(row0 + r) * DM + col] = acc[mi][ni][r] + bb;
        }
    }
}

// ---------------------------------------------------------------------------
extern "C" void kernel_launch(void* const* d_in, const int* in_sizes, int n_in,
                              void* d_out, int out_size, void* d_ws, size_t ws_size,
                              hipStream_t stream) {
    const float* x0 = (const float*)d_in[0];
    const float* x1 = (const float*)d_in[1];
    const float* x2 = (const float*)d_in[2];
    const float* Wq = (const float*)d_in[3];
    const float* bq = (const float*)d_in[4];
    const float* Wk = (const float*)d_in[5];
    const float* bk = (const float*)d_in[6];
    const float* Wv = (const float*)d_in[7];
    const float* bv = (const float*)d_in[8];
    const float* Wo = (const float*)d_in[9];
    const float* bo = (const float*)d_in[10];
    float* out = (float*)d_out;

    // bf16 workspace, ~39 MB
    __bf16* xb0 = (__bf16*)d_ws;        // 2M
    __bf16* xb1 = xb0 + 2 * M1;         // 1M
    __bf16* xb2 = xb1 + M1;             // 0.5M
    __bf16* Wqb = xb2 + M1 / 2;         // 3M
    __bf16* Wkb = Wqb + 3 * M1;         // 3M
    __bf16* Wvb = Wkb + 3 * M1;         // 1M
    __bf16* Wob = Wvb + M1;             // 1M
    __bf16* vt0 = Wob + M1;             // 2M
    __bf16* vt1 = vt0 + 2 * M1;         // 1M
    __bf16* vt2 = vt1 + M1;             // 0.5M
    __bf16* qb0 = vt2 + M1 / 2;         // 2M
    __bf16* kb0 = qb0 + 2 * M1;         // 2M
    __bf16* qb1 = kb0 + 2 * M1;         // 1M
    __bf16* kb1 = qb1 + M1;             // 1M
    __bf16* qb2 = kb1 + M1;             // 0.5M
    __bf16* kb2 = qb2 + M1 / 2;         // 0.5M

    // 1. convert everything to bf16
    cvt_all<<<5888, 256, 0, stream>>>(x0, x1, x2, Wq, Wk, Wv, Wo,
                                      xb0, xb1, xb2, Wqb, Wkb, Wvb, Wob);
    // 2. all pre-attention GEMMs (flat grid, dbuf LDS core, XCD chunked)
    gemm_pre<<<576, 256, 0, stream>>>(xb0, xb1, xb2, Wqb, Wkb, Wvb,
                                      bq, bk, bv,
                                      qb0, kb0, qb1, kb1, qb2, kb2,
                                      vt0, vt1, vt2);
    // 3. attention, all scales; 32-row waves, split-K, XCD head affinity
    attn_all<<<1792, 256, 0, stream>>>(qb0, kb0, vt0, qb0,
                                       qb1, kb1, vt1, qb1,
                                       qb2, kb2, vt2, qb2);
    // 4. output projections (flat grid, dbuf LDS core), f32 into d_out
    gemm_out_all<<<224, 256, 0, stream>>>(qb0, qb1, qb2, Wob, bo, out);
}

// Round 13
// 143.303 us; speedup vs baseline: 2.1042x; 1.3300x over previous
//
#include <hip/hip_runtime.h>
#include <hip/hip_bf16.h>
#include <math.h>

typedef __bf16 bf16x8 __attribute__((ext_vector_type(8)));
typedef __bf16 bf16x4 __attribute__((ext_vector_type(4)));
typedef __bf16 bf16x2 __attribute__((ext_vector_type(2)));
typedef float f32x4 __attribute__((ext_vector_type(4)));
typedef float f32x16 __attribute__((ext_vector_type(16)));

static constexpr int DM = 1024;    // d_model
static constexpr int HD = 64;      // head dim
static constexpr size_t M1 = 1024 * 1024;

// pack two f32 -> u32 of two bf16 (compiler emits v_cvt_pk_bf16_f32)
__device__ __forceinline__ unsigned pk2(float a, float b) {
    union { __bf16 h[2]; unsigned u; } t;
    t.h[0] = (__bf16)a; t.h[1] = (__bf16)b;
    return t.u;
}

// async global->LDS, 16 B per lane; LDS dest = wave-uniform base + lane*16
typedef const __attribute__((address_space(1))) unsigned int* gp_t;
typedef __attribute__((address_space(3))) unsigned int* lp_t;
__device__ __forceinline__ void gload_lds16(const void* g, void* l) {
    __builtin_amdgcn_global_load_lds((gp_t)g, (lp_t)l, 16, 0, 0);
}

// ---------------------------------------------------------------------------
// Fused f32->bf16 convert of all 7 tensors, one launch.
// ---------------------------------------------------------------------------
__global__ void cvt_all(const float* __restrict__ x0, const float* __restrict__ x1,
                        const float* __restrict__ x2, const float* __restrict__ Wq,
                        const float* __restrict__ Wk, const float* __restrict__ Wv,
                        const float* __restrict__ Wo,
                        __bf16* __restrict__ xb0, __bf16* __restrict__ xb1,
                        __bf16* __restrict__ xb2, __bf16* __restrict__ Wqb,
                        __bf16* __restrict__ Wkb, __bf16* __restrict__ Wvb,
                        __bf16* __restrict__ Wob) {
    size_t i = (size_t)(blockIdx.x * blockDim.x + threadIdx.x) * 8;
    const float* in; __bf16* outp; size_t off;
    if      (i < 2 * M1)            { in = x0; outp = xb0; off = i; }
    else if (i < 3 * M1)            { in = x1; outp = xb1; off = i - 2 * M1; }
    else if (i < 3 * M1 + M1 / 2)   { in = x2; outp = xb2; off = i - 3 * M1; }
    else if (i < 6 * M1 + M1 / 2)   { in = Wq; outp = Wqb; off = i - (3 * M1 + M1 / 2); }
    else if (i < 9 * M1 + M1 / 2)   { in = Wk; outp = Wkb; off = i - (6 * M1 + M1 / 2); }
    else if (i < 10 * M1 + M1 / 2)  { in = Wv; outp = Wvb; off = i - (9 * M1 + M1 / 2); }
    else if (i < 11 * M1 + M1 / 2)  { in = Wo; outp = Wob; off = i - (10 * M1 + M1 / 2); }
    else return;
    const float4 a = *reinterpret_cast<const float4*>(in + off);
    const float4 b = *reinterpret_cast<const float4*>(in + off + 4);
    bf16x8 r;
    r[0] = (__bf16)a.x; r[1] = (__bf16)a.y; r[2] = (__bf16)a.z; r[3] = (__bf16)a.w;
    r[4] = (__bf16)b.x; r[5] = (__bf16)b.y; r[6] = (__bf16)b.z; r[7] = (__bf16)b.w;
    *reinterpret_cast<bf16x8*>(outp + off) = r;
}

// ---------------------------------------------------------------------------
// GEMM core v3: 128x128 block tile, 4 waves (2x2) of 64x64, BK=32, dbuf LDS.
// COALESCED staging: LDS tile [128 rows][32 k] bf16 (row = 64 B); lane s:
// row = s>>2, chunk = (s&3) ^ swz(row), swz = (row^(row>>2))&3 — source lanes
// cover full 64B lines (16 transactions/inst); frag ds_read_b128 at
// row*32 + (g^swz(row))*8 — 8 lanes/bank-quad, conflict-free (both-sides XOR).
// C/D layout: row=(lane>>4)*4+reg, col=lane&15 (m89-verified)
// ---------------------------------------------------------------------------
__device__ __forceinline__ void gemm_lds_core(const __bf16* __restrict__ A,
                                              const __bf16* __restrict__ W,
                                              int rb, int cb, int tix,
                                              __bf16* lA, __bf16* lB,
                                              f32x4 (&acc)[4][4]) {
    const int lane = tix & 63;
    const int w = tix >> 6;
    const int g = lane >> 4, t = lane & 15;
    // staging: inst0 slot s=tix (rows 0..63), inst1 s=tix+256 (rows 64..127)
    const int r0 = tix >> 2;
    const int r1 = r0 + 64;
    const int c0 = (tix & 3) ^ ((r0 ^ (r0 >> 2)) & 3);
    const int c1 = (tix & 3) ^ ((r1 ^ (r1 >> 2)) & 3);
    const __bf16* a0 = A + (size_t)(rb + r0) * DM + c0 * 8;
    const __bf16* a1 = A + (size_t)(rb + r1) * DM + c1 * 8;
    const __bf16* b0 = W + (size_t)(cb + r0) * DM + c0 * 8;
    const __bf16* b1 = W + (size_t)(cb + r1) * DM + c1 * 8;
    const int d0 = w * 512;            // elem offset of wave's inst0 slot base
    const int d1 = 2048 + w * 512;     // inst1
    const int rw = (w >> 1) * 64, cw = (w & 1) * 64;
    // frag read offsets (elems): row*32 + (g^swz(row))*8
    int roA[4], roB[4];
#pragma unroll
    for (int i = 0; i < 4; ++i) {
        const int ra = rw + i * 16 + t;
        const int rbr = cw + i * 16 + t;
        roA[i] = ra * 32 + ((g ^ ((ra ^ (ra >> 2)) & 3)) * 8);
        roB[i] = rbr * 32 + ((g ^ ((rbr ^ (rbr >> 2)) & 3)) * 8);
    }

    // prologue: stage step 0 into buffer 0
    gload_lds16(a0, lA + d0);
    gload_lds16(a1, lA + d1);
    gload_lds16(b0, lB + d0);
    gload_lds16(b1, lB + d1);
    __syncthreads();

    int cur = 0;
    for (int kk = 0; kk < DM; kk += 32) {
        if (kk + 32 < DM) {
            __bf16* nA = lA + (cur ^ 1) * 4096;
            __bf16* nB = lB + (cur ^ 1) * 4096;
            gload_lds16(a0 + kk + 32, nA + d0);
            gload_lds16(a1 + kk + 32, nA + d1);
            gload_lds16(b0 + kk + 32, nB + d0);
            gload_lds16(b1 + kk + 32, nB + d1);
        }
        const __bf16* bA = lA + cur * 4096;
        const __bf16* bB = lB + cur * 4096;
        bf16x8 af[4], bfr[4];
#pragma unroll
        for (int i = 0; i < 4; ++i) {
            af[i]  = *reinterpret_cast<const bf16x8*>(bA + roA[i]);
            bfr[i] = *reinterpret_cast<const bf16x8*>(bB + roB[i]);
        }
#pragma unroll
        for (int mi = 0; mi < 4; ++mi)
#pragma unroll
            for (int ni = 0; ni < 4; ++ni)
                acc[mi][ni] = __builtin_amdgcn_mfma_f32_16x16x32_bf16(af[mi], bfr[ni], acc[mi][ni], 0, 0, 0);
        __syncthreads();    // drains next-step loads (issued before compute)
        cur ^= 1;
    }
}

// ---------------------------------------------------------------------------
// All pre-attention GEMMs, flat 1-D grid of 576 blocks:
//   z=0,2,4: Q proj + fused RoPE + 1/8 scale | z=1,3,5: K proj + RoPE
//   z=6: V proj -> transposed vt0 + fused avg-pool into vt1, vt2
// Chunked XCD swizzle: swz=(bid&7)*72+(bid>>3) (576=8*72, bijective).
// ---------------------------------------------------------------------------
__global__ __launch_bounds__(256)
void gemm_pre(const __bf16* __restrict__ xb0, const __bf16* __restrict__ xb1,
              const __bf16* __restrict__ xb2, const __bf16* __restrict__ Wqb,
              const __bf16* __restrict__ Wkb, const __bf16* __restrict__ Wvb,
              const float* __restrict__ bq, const float* __restrict__ bk,
              const float* __restrict__ bv,
              __bf16* __restrict__ qb0, __bf16* __restrict__ kb0,
              __bf16* __restrict__ qb1, __bf16* __restrict__ kb1,
              __bf16* __restrict__ qb2, __bf16* __restrict__ kb2,
              __bf16* __restrict__ vt0, __bf16* __restrict__ vt1,
              __bf16* __restrict__ vt2) {
    __shared__ __align__(16) __bf16 lA[8192], lB[8192];   // 32 KB (2 buffers)
    const int bid = blockIdx.x;
    const int swz = (bid & 7) * 72 + (bid >> 3);
    int z, local, mblk;
    if      (swz < 128) { z = 0; local = swz;       mblk = 16; }
    else if (swz < 256) { z = 1; local = swz - 128; mblk = 16; }
    else if (swz < 320) { z = 2; local = swz - 256; mblk = 8;  }
    else if (swz < 384) { z = 3; local = swz - 320; mblk = 8;  }
    else if (swz < 416) { z = 4; local = swz - 384; mblk = 4;  }
    else if (swz < 448) { z = 5; local = swz - 416; mblk = 4;  }
    else                { z = 6; local = swz - 448; mblk = 16; }
    const __bf16* A; const __bf16* W; const float* bias; __bf16* out;
    switch (z) {
        case 0:  A = xb0; W = Wqb;          bias = bq;        out = qb0; break;
        case 1:  A = xb0; W = Wkb;          bias = bk;        out = kb0; break;
        case 2:  A = xb1; W = Wqb + M1;     bias = bq + 1024; out = qb1; break;
        case 3:  A = xb1; W = Wkb + M1;     bias = bk + 1024; out = kb1; break;
        case 4:  A = xb2; W = Wqb + 2 * M1; bias = bq + 2048; out = qb2; break;
        case 5:  A = xb2; W = Wkb + 2 * M1; bias = bk + 2048; out = kb2; break;
        default: A = xb0; W = Wvb;          bias = bv;        out = nullptr; break;
    }
    const int rb = (local % mblk) * 128;
    const int cb = (local / mblk) * 128;
    const int tix = threadIdx.x;
    f32x4 acc[4][4] = {};
    gemm_lds_core(A, W, rb, cb, tix, lA, lB, acc);

    const int lane = tix & 63;
    const int w = tix >> 6;
    const int g = lane >> 4, t = lane & 15;
    const int rbw = rb + (w >> 1) * 64;
    const int cbw = cb + (w & 1) * 64;     // head-aligned 64-col span

    if (z == 6) {
        // V projection epilogue: transposed store + fused avg-pool
#pragma unroll
        for (int ni = 0; ni < 4; ++ni) {
            const int col = cbw + ni * 16 + t;          // d dim
            const float bb = bias[col];
#pragma unroll
            for (int mi = 0; mi < 4; ++mi) {
                const int row0 = rbw + mi * 16 + g * 4; // n dim
                const f32x4 a = acc[mi][ni];
                bf16x4 pk;
#pragma unroll
                for (int r = 0; r < 4; ++r) pk[r] = (__bf16)(a[r] + bb);
                *reinterpret_cast<bf16x4*>(vt0 + (size_t)col * 2048 + row0) = pk;
                bf16x2 p2;
                p2[0] = (__bf16)(0.5f * (a[0] + a[1]) + bb);
                p2[1] = (__bf16)(0.5f * (a[2] + a[3]) + bb);
                *reinterpret_cast<bf16x2*>(vt1 + (size_t)col * 1024 + row0 / 2) = p2;
                vt2[(size_t)col * 512 + row0 / 4] =
                    (__bf16)(0.25f * (a[0] + a[1] + a[2] + a[3]) + bb);
            }
        }
    } else {
        // Q/K epilogue with fused RoPE; Q additionally scaled by 1/8
        const float qmul = (z & 1) ? 1.0f : 0.125f;
        const float ps = (float)(1 << (z >> 1));   // 1,2,4
#pragma unroll
        for (int ni = 0; ni < 2; ++ni) {
            const int j = ni * 16 + t;             // [0,32) within head
            const float invf = __expf(-(float)j * 0.28782313662425576f);
            const float b1 = bias[cbw + j];
            const float b2 = bias[cbw + j + 32];
#pragma unroll
            for (int mi = 0; mi < 4; ++mi) {
#pragma unroll
                for (int r = 0; r < 4; ++r) {
                    const int row = rbw + mi * 16 + g * 4 + r;
                    float c, s;
                    __sincosf((float)row * ps * invf, &s, &c);
                    const float x1 = acc[mi][ni][r] + b1;
                    const float x2 = acc[mi][ni + 2][r] + b2;
                    out[(size_t)row * DM + cbw + j]      = (__bf16)((x1 * c - x2 * s) * qmul);
                    out[(size_t)row * DM + cbw + j + 32] = (__bf16)((x1 * s + x2 * c) * qmul);
                }
            }
        }
    }
}

// ---------------------------------------------------------------------------
// MFMA flash attention v7: 32-row waves, swapped QK^T, lane-local softmax,
// PER-WAVE COALESCED LDS STAGING of K and V tiles (global_load_lds is
// wave-scope -> no barriers; explicit vmcnt(0) before ds_reads).
//   K tile [32 rows][128B], source chunk ^ (row&7) swizzle -> frag reads
//   conflict-free; V tile [64 rows][64B], chunk ^ (row&3) swizzle.
// P-bounce reuses the (dead after frag reads) K staging region.
// Split-K across 4 waves; NO-MAX softmax -> partials add; final LDS combine
// (overlaid on staging, after __syncthreads).
// XCD affinity: 1792 blocks = 8 x 224; job=(bid&7)*224+(bid>>3); 2 heads/XCD.
// ---------------------------------------------------------------------------
__global__ __launch_bounds__(256)
void attn_all(const __bf16* __restrict__ qb0, const __bf16* __restrict__ kb0,
              const __bf16* __restrict__ vt0, __bf16* __restrict__ ctx0,
              const __bf16* __restrict__ qb1, const __bf16* __restrict__ kb1,
              const __bf16* __restrict__ vt1, __bf16* __restrict__ ctx1,
              const __bf16* __restrict__ qb2, const __bf16* __restrict__ kb2,
              const __bf16* __restrict__ vt2, __bf16* __restrict__ ctx2) {
    __shared__ __align__(16) float shm[4 * 64 * 33];    // 33.8 KB
    // loop phase: per-wave staging (K 4KB + V 4KB at w*8KB); epilogue: combine
    const int bid = blockIdx.x;
    const int job = (bid & 7) * 224 + (bid >> 3);
    const int h = job / 112;
    int rem = job % 112;
    const __bf16 *qb, *kb, *vt; __bf16* ctx; int N, nq;
    if (rem < 64)      { qb = qb0; kb = kb0; vt = vt0; ctx = ctx0; N = 2048; nq = 64; }
    else if (rem < 96) { rem -= 64; qb = qb1; kb = kb1; vt = vt1; ctx = ctx1; N = 1024; nq = 32; }
    else               { rem -= 96; qb = qb2; kb = kb2; vt = vt2; ctx = ctx2; N = 512;  nq = 16; }
    const int qt = (rem & 1) ? (nq - 1 - (rem >> 1)) : (rem >> 1);
    const int lane = threadIdx.x & 63;
    const int w = threadIdx.x >> 6;
    const int q0 = qt * 32;
    const int lq = lane & 31;
    const int hi = lane >> 5;

    __bf16* Kl = (__bf16*)shm + (size_t)w * 4096;   // [32][64 elems] (4 KB)
    __bf16* Vl = Kl + 2048;                          // [64][32 elems] (4 KB)

    // Q B-frags: lane holds Q[q0+lq][h*64 + dc*16 + hi*8 + 0..7]
    const __bf16* qp = qb + (size_t)(q0 + lq) * DM + h * HD + hi * 8;
    bf16x8 qf[4];
#pragma unroll
    for (int dc = 0; dc < 4; ++dc)
        qf[dc] = *reinterpret_cast<const bf16x8*>(qp + dc * 16);

    f32x16 o0 = {}, o1 = {};
    float lsum = 0.f;
    const int ktiles = qt + 1;

    // staging source addressing (per lane, constant parts)
    const int krow = lane >> 3, kch = lane & 7;      // K: 8 lanes/row (128B)
    const int vrow = lane >> 2, vch = lane & 3;      // V: 4 lanes/row (64B)
    // K inst j: rows j*8 + krow ... (4 insts x 8 rows = 32 rows)
    // V inst j: rows j*16 + vrow ... (4 insts x 16 rows = 64 rows)

    // K frag read offsets (elems): row lq, chunk (dc*2+hi)^(lq&7)
    int koff[4];
#pragma unroll
    for (int dc = 0; dc < 4; ++dc)
        koff[dc] = lq * 64 + (((dc * 2 + hi) ^ (lq & 7)) * 8);
    // V frag read offsets: rows lq / 32+lq, chunk (kc*2+hi)^(row&3)
    const int v00o = lq * 32 + ((hi ^ (lq & 3)) * 8);
    const int v01o = lq * 32 + (((2 + hi) ^ (lq & 3)) * 8);
    const int v10o = (32 + lq) * 32 + ((hi ^ (lq & 3)) * 8);
    const int v11o = (32 + lq) * 32 + (((2 + hi) ^ (lq & 3)) * 8);

    unsigned* pw = (unsigned*)Kl + lq * 18;          // P-bounce inside K region
    const __bf16* prb = (const __bf16*)pw;

    for (int kt = w; kt < ktiles; kt += 4) {
        const int j0 = kt * 32;
        // stage K tile (4 insts, coalesced 128B rows, swizzled source)
#pragma unroll
        for (int j = 0; j < 4; ++j) {
            const int row = j * 8 + krow;
            gload_lds16(kb + (size_t)(j0 + row) * DM + h * HD + ((kch ^ (row & 7)) * 8),
                        Kl + j * 512);
        }
        // stage V tile (4 insts, coalesced 64B rows, swizzled source)
#pragma unroll
        for (int j = 0; j < 4; ++j) {
            const int row = j * 16 + vrow;
            gload_lds16(vt + (size_t)(h * HD + row) * N + j0 + ((vch ^ (row & 3)) * 8),
                        Vl + j * 512);
        }
        asm volatile("s_waitcnt vmcnt(0)" ::: "memory");

        // K frags from LDS
        bf16x8 kf[4];
#pragma unroll
        for (int dc = 0; dc < 4; ++dc)
            kf[dc] = *reinterpret_cast<const bf16x8*>(Kl + koff[dc]);
        // V frags from LDS
        const bf16x8 v00 = *reinterpret_cast<const bf16x8*>(Vl + v00o);
        const bf16x8 v01 = *reinterpret_cast<const bf16x8*>(Vl + v01o);
        const bf16x8 v10 = *reinterpret_cast<const bf16x8*>(Vl + v10o);
        const bf16x8 v11 = *reinterpret_cast<const bf16x8*>(Vl + v11o);

        // QK^T (swapped): p[r] = S[key j0+(r&3)+8*(r>>2)+4*hi][q-row q0+lq]
        f32x16 p = {};
        p = __builtin_amdgcn_mfma_f32_32x32x16_bf16(kf[0], qf[0], p, 0, 0, 0);
        p = __builtin_amdgcn_mfma_f32_32x32x16_bf16(kf[1], qf[1], p, 0, 0, 0);
        p = __builtin_amdgcn_mfma_f32_32x32x16_bf16(kf[2], qf[2], p, 0, 0, 0);
        p = __builtin_amdgcn_mfma_f32_32x32x16_bf16(kf[3], qf[3], p, 0, 0, 0);

        // causal mask + exp (no max tracking), lane-local denominator
#pragma unroll
        for (int r = 0; r < 16; ++r) {
            const int key = j0 + (r & 3) + 8 * (r >> 2) + 4 * hi;
            p[r] = (key <= q0 + lq) ? __expf(p[r]) : 0.f;
            lsum += p[r];
        }

        // P-bounce (K region is dead): write packed pairs at C/D key slots
        pw[2 * hi]      = pk2(p[0],  p[1]);
        pw[2 * hi + 1]  = pk2(p[2],  p[3]);
        pw[4 + 2 * hi]  = pk2(p[4],  p[5]);
        pw[5 + 2 * hi]  = pk2(p[6],  p[7]);
        pw[8 + 2 * hi]  = pk2(p[8],  p[9]);
        pw[9 + 2 * hi]  = pk2(p[10], p[11]);
        pw[12 + 2 * hi] = pk2(p[12], p[13]);
        pw[13 + 2 * hi] = pk2(p[14], p[15]);
        union U8 { bf16x4 half[2]; bf16x8 v; };
        U8 pf0, pf1;
        pf0.half[0] = *reinterpret_cast<const bf16x4*>(prb + hi * 8);
        pf0.half[1] = *reinterpret_cast<const bf16x4*>(prb + hi * 8 + 4);
        pf1.half[0] = *reinterpret_cast<const bf16x4*>(prb + 16 + hi * 8);
        pf1.half[1] = *reinterpret_cast<const bf16x4*>(prb + 16 + hi * 8 + 4);

        // PV: O^T[d][q] += V^T[d][k] * P[k][q]
        o0 = __builtin_amdgcn_mfma_f32_32x32x16_bf16(v00, pf0.v, o0, 0, 0, 0);
        o0 = __builtin_amdgcn_mfma_f32_32x32x16_bf16(v01, pf1.v, o0, 0, 0, 0);
        o1 = __builtin_amdgcn_mfma_f32_32x32x16_bf16(v10, pf0.v, o1, 0, 0, 0);
        o1 = __builtin_amdgcn_mfma_f32_32x32x16_bf16(v11, pf1.v, o1, 0, 0, 0);
    }

    __syncthreads();   // staging/P regions dead in all waves -> overlay combine
    float* cmb = shm;
    float* my = cmb + ((size_t)w * 64 + lane) * 33;
#pragma unroll
    for (int i = 0; i < 16; ++i) { my[i] = o0[i]; my[16 + i] = o1[i]; }
    my[32] = lsum;
    __syncthreads();
    float tot[8] = {};
    float lt = 0.f;
#pragma unroll
    for (int w2 = 0; w2 < 4; ++w2) {
        const float* src = cmb + ((size_t)w2 * 64 + lane) * 33;
#pragma unroll
        for (int j = 0; j < 8; ++j) tot[j] += src[8 * w + j];
        lt += src[32];
    }
    lt += __shfl_xor(lt, 32);
    const float inv = 1.0f / lt;
    // slot 8w+j holds d = 32*(w>>1) + 16*(w&1) + 8*(j>>2) + 4*hi + (j&3)
    const int dbase = 32 * (w >> 1) + 16 * (w & 1) + 4 * hi;
    __bf16* cp = ctx + (size_t)(q0 + lq) * DM + h * HD;
    bf16x4 s0, s1;
#pragma unroll
    for (int j = 0; j < 4; ++j) {
        s0[j] = (__bf16)(tot[j] * inv);
        s1[j] = (__bf16)(tot[4 + j] * inv);
    }
    *reinterpret_cast<bf16x4*>(cp + dbase) = s0;
    *reinterpret_cast<bf16x4*>(cp + dbase + 8) = s1;
}

// ---------------------------------------------------------------------------
// Output projections, flat grid of 224 blocks (8x28 chunked XCD swizzle).
// ---------------------------------------------------------------------------
__global__ __launch_bounds__(256)
void gemm_out_all(const __bf16* __restrict__ c0, const __bf16* __restrict__ c1,
                  const __bf16* __restrict__ c2, const __bf16* __restrict__ Wob,
                  const float* __restrict__ bo, float* __restrict__ out) {
    __shared__ __align__(16) __bf16 lA[8192], lB[8192];
    const int bid = blockIdx.x;
    const int swz = (bid & 7) * 28 + (bid >> 3);     // 224 = 8*28
    int z, local, mblk;
    if      (swz < 128) { z = 0; local = swz;       mblk = 16; }
    else if (swz < 192) { z = 1; local = swz - 128; mblk = 8;  }
    else                { z = 2; local = swz - 192; mblk = 4;  }
    const __bf16* A; float* o;
    switch (z) {
        case 0:  A = c0; o = out;             break;
        case 1:  A = c1; o = out + 2048 * DM; break;
        default: A = c2; o = out + 3072 * DM; break;
    }
    const int rb = (local % mblk) * 128;
    const int cb = (local / mblk) * 128;
    const int tix = threadIdx.x;
    f32x4 acc[4][4] = {};
    gemm_lds_core(A, Wob, rb, cb, tix, lA, lB, acc);

    const int lane = tix & 63;
    const int w = tix >> 6;
    const int g = lane >> 4, t = lane & 15;
    const int rbw = rb + (w >> 1) * 64;
    const int cbw = cb + (w & 1) * 64;
#pragma unroll
    for (int ni = 0; ni < 4; ++ni) {
        const int col = cbw + ni * 16 + t;
        const float bb = bo[col];
#pragma unroll
        for (int mi = 0; mi < 4; ++mi) {
            const int row0 = rbw + mi * 16 + g * 4;
#pragma unroll
            for (int r = 0; r < 4; ++r)
                o[(size_t)(row0 + r) * DM + col] = acc[mi][ni][r] + bb;
        }
    }
}

// ---------------------------------------------------------------------------
extern "C" void kernel_launch(void* const* d_in, const int* in_sizes, int n_in,
                              void* d_out, int out_size, void* d_ws, size_t ws_size,
                              hipStream_t stream) {
    const float* x0 = (const float*)d_in[0];
    const float* x1 = (const float*)d_in[1];
    const float* x2 = (const float*)d_in[2];
    const float* Wq = (const float*)d_in[3];
    const float* bq = (const float*)d_in[4];
    const float* Wk = (const float*)d_in[5];
    const float* bk = (const float*)d_in[6];
    const float* Wv = (const float*)d_in[7];
    const float* bv = (const float*)d_in[8];
    const float* Wo = (const float*)d_in[9];
    const float* bo = (const float*)d_in[10];
    float* out = (float*)d_out;

    // bf16 workspace, ~39 MB
    __bf16* xb0 = (__bf16*)d_ws;        // 2M
    __bf16* xb1 = xb0 + 2 * M1;         // 1M
    __bf16* xb2 = xb1 + M1;             // 0.5M
    __bf16* Wqb = xb2 + M1 / 2;         // 3M
    __bf16* Wkb = Wqb + 3 * M1;         // 3M
    __bf16* Wvb = Wkb + 3 * M1;         // 1M
    __bf16* Wob = Wvb + M1;             // 1M
    __bf16* vt0 = Wob + M1;             // 2M
    __bf16* vt1 = vt0 + 2 * M1;         // 1M
    __bf16* vt2 = vt1 + M1;             // 0.5M
    __bf16* qb0 = vt2 + M1 / 2;         // 2M
    __bf16* kb0 = qb0 + 2 * M1;         // 2M
    __bf16* qb1 = kb0 + 2 * M1;         // 1M
    __bf16* kb1 = qb1 + M1;             // 1M
    __bf16* qb2 = kb1 + M1;             // 0.5M
    __bf16* kb2 = qb2 + M1 / 2;         // 0.5M

    // 1. convert everything to bf16
    cvt_all<<<5888, 256, 0, stream>>>(x0, x1, x2, Wq, Wk, Wv, Wo,
                                      xb0, xb1, xb2, Wqb, Wkb, Wvb, Wob);
    // 2. all pre-attention GEMMs (coalesced LDS core, XCD chunked)
    gemm_pre<<<576, 256, 0, stream>>>(xb0, xb1, xb2, Wqb, Wkb, Wvb,
                                      bq, bk, bv,
                                      qb0, kb0, qb1, kb1, qb2, kb2,
                                      vt0, vt1, vt2);
    // 3. attention: per-wave coalesced K/V staging, split-K, XCD affinity
    attn_all<<<1792, 256, 0, stream>>>(qb0, kb0, vt0, qb0,
                                       qb1, kb1, vt1, qb1,
                                       qb2, kb2, vt2, qb2);
    // 4. output projections, f32 into d_out
    gemm_out_all<<<224, 256, 0, stream>>>(qb0, qb1, qb2, Wob, bo, out);
}